// Round 2
// baseline (2107.162 us; speedup 1.0000x reference)
//
#include <hip/hip_runtime.h>
#include <hip/hip_bf16.h>

using bf16 = __hip_bfloat16;

// ---------------- helpers ----------------
__device__ __forceinline__ float tof(float v) { return v; }
__device__ __forceinline__ float tof(bf16 v) { return __bfloat162float(v); }

__device__ __forceinline__ void storev(float* p, float v) { *p = v; }
__device__ __forceinline__ void storev(bf16* p, float v) { *p = __float2bfloat16(v); }

__device__ __forceinline__ void load4(const float* p, float* o) {
    float4 v = *(const float4*)p;
    o[0] = v.x; o[1] = v.y; o[2] = v.z; o[3] = v.w;
}
__device__ __forceinline__ void load4(const bf16* p, float* o) {
    ushort4 u = *(const ushort4*)p;
    o[0] = __uint_as_float(((unsigned)u.x) << 16);
    o[1] = __uint_as_float(((unsigned)u.y) << 16);
    o[2] = __uint_as_float(((unsigned)u.z) << 16);
    o[3] = __uint_as_float(((unsigned)u.w) << 16);
}

__device__ __forceinline__ float wsum(float v) {
    #pragma unroll
    for (int o = 32; o > 0; o >>= 1) v += __shfl_xor(v, o);
    return v;
}
__device__ __forceinline__ float wmax(float v) {
    #pragma unroll
    for (int o = 32; o > 0; o >>= 1) v = fmaxf(v, __shfl_xor(v, o));
    return v;
}

// ---------------- LayerNorm over channel dim (per pixel) ----------------
__global__ __launch_bounds__(256) void ln_kernel(
    const float* __restrict__ X, const float* __restrict__ w,
    const float* __restrict__ bias, float* __restrict__ Y, int C, int N)
{
    const int pg = blockIdx.x * 256 + threadIdx.x;  // over B*N
    const int b = pg / N, n = pg % N;
    const float* xp = X + (size_t)b * C * N + n;
    float s = 0.f, s2 = 0.f;
    for (int c = 0; c < C; c++) { float v = xp[(size_t)c * N]; s += v; s2 += v * v; }
    const float mean = s / C;
    const float var = s2 / C - mean * mean;
    const float rstd = rsqrtf(var + 1e-5f);
    float* yp = Y + (size_t)b * C * N + n;
    for (int c = 0; c < C; c++) {
        float v = xp[(size_t)c * N];
        yp[(size_t)c * N] = (v - mean) * rstd * w[c] + bias[c];
    }
}

// ---------------- conv1x1 = GEMM: Y[b,o,n] = sum_c W[o*Wld+c]*X[b,c,n] (+R) ----------------
template<typename XT, typename YT, bool RESID>
__global__ __launch_bounds__(256) void conv1x1_kernel(
    const XT* __restrict__ X, const float* __restrict__ W, int Wld,
    const float* __restrict__ R, YT* __restrict__ Y,
    int O, int C, int N)
{
    __shared__ float Xs[16][64];
    __shared__ float Ws[16][64];
    const int b = blockIdx.z;
    const int n0 = blockIdx.x * 64;
    const int o0 = blockIdx.y * 64;
    const int tid = threadIdx.x;
    const int tx = tid & 15, ty = tid >> 4;
    float acc[4][4] = {};
    const XT* Xb = X + (size_t)b * C * N;

    for (int c0 = 0; c0 < C; c0 += 16) {
        {
            const int r = tid >> 4, col = (tid & 15) << 2;
            const int c = c0 + r;
            float tmp[4] = {0.f, 0.f, 0.f, 0.f};
            if (c < C) load4(Xb + (size_t)c * N + n0 + col, tmp);
            Xs[r][col] = tmp[0]; Xs[r][col + 1] = tmp[1];
            Xs[r][col + 2] = tmp[2]; Xs[r][col + 3] = tmp[3];
        }
        {
            const int ol = tid & 63, kb = (tid >> 6) << 2;
            const int o = o0 + ol;
            const float* wp = W + (size_t)o * Wld + c0 + kb;
            #pragma unroll
            for (int j = 0; j < 4; j++) {
                float v = 0.f;
                if (o < O && (c0 + kb + j) < C) v = wp[j];
                Ws[kb + j][ol] = v;
            }
        }
        __syncthreads();
        #pragma unroll
        for (int kk = 0; kk < 16; kk++) {
            const float4 xv = *(const float4*)&Xs[kk][tx << 2];
            const float4 wv = *(const float4*)&Ws[kk][ty << 2];
            acc[0][0] += wv.x * xv.x; acc[0][1] += wv.x * xv.y; acc[0][2] += wv.x * xv.z; acc[0][3] += wv.x * xv.w;
            acc[1][0] += wv.y * xv.x; acc[1][1] += wv.y * xv.y; acc[1][2] += wv.y * xv.z; acc[1][3] += wv.y * xv.w;
            acc[2][0] += wv.z * xv.x; acc[2][1] += wv.z * xv.y; acc[2][2] += wv.z * xv.z; acc[2][3] += wv.z * xv.w;
            acc[3][0] += wv.w * xv.x; acc[3][1] += wv.w * xv.y; acc[3][2] += wv.w * xv.z; acc[3][3] += wv.w * xv.w;
        }
        __syncthreads();
    }
    const size_t ybase = (size_t)b * O * N;
    #pragma unroll
    for (int i = 0; i < 4; i++) {
        const int o = o0 + ty * 4 + i;
        if (o < O) {
            const size_t rowoff = ybase + (size_t)o * N + n0 + (tx << 2);
            #pragma unroll
            for (int j = 0; j < 4; j++) {
                float v = acc[i][j];
                if (RESID) v += R[rowoff + j];
                storev(Y + rowoff + j, v);
            }
        }
    }
}

// ---------------- depthwise 3x3, SAME, H=W=128 ----------------
template<typename T>
__global__ __launch_bounds__(256) void dwconv3_kernel(
    const T* __restrict__ X, const float* __restrict__ Wd, T* __restrict__ Y,
    int CH, int HW)
{
    const int pix = blockIdx.x * 256 + threadIdx.x;
    const int ch = blockIdx.y, b = blockIdx.z;
    const int py = pix >> 7, px = pix & 127;
    const size_t base = ((size_t)b * CH + ch) * HW;
    const float* w = Wd + ch * 9;
    float s = 0.f;
    #pragma unroll
    for (int dy = -1; dy <= 1; dy++) {
        const int yy = py + dy;
        if (yy < 0 || yy > 127) continue;
        #pragma unroll
        for (int dx = -1; dx <= 1; dx++) {
            const int xx = px + dx;
            if (xx < 0 || xx > 127) continue;
            s += w[(dy + 1) * 3 + (dx + 1)] * tof(X[base + yy * 128 + xx]);
        }
    }
    storev(Y + base + pix, s);
}

// ---------------- row L2 norms: inv[row], rows contiguous of length N ----------------
__global__ __launch_bounds__(256) void rownorm_kernel(
    const float* __restrict__ X, float* __restrict__ inv, int N)
{
    const int row = blockIdx.x;
    const float* p = X + (size_t)row * N;
    float s = 0.f;
    for (int i = threadIdx.x; i < N; i += 256) { float v = p[i]; s += v * v; }
    s = wsum(s);
    __shared__ float red[4];
    if ((threadIdx.x & 63) == 0) red[threadIdx.x >> 6] = s;
    __syncthreads();
    if (threadIdx.x == 0) {
        float t = red[0] + red[1] + red[2] + red[3];
        inv[row] = 1.f / fmaxf(sqrtf(t), 1e-12f);
    }
}

// ---------------- gram: attn_raw[bh,c,d] += sum_n q*k ; Q,K are [B][192][N] ----------------
__global__ __launch_bounds__(256) void gram_kernel(
    const float* __restrict__ Q, const float* __restrict__ K,
    float* __restrict__ attn_raw, int N)
{
    __shared__ float qs[48][65];
    __shared__ float ks[48][65];
    const int b = blockIdx.z, h = blockIdx.y;
    const int nbase = blockIdx.x * 1024;
    const float* Qb = Q + ((size_t)b * 192 + h * 48) * N;
    const float* Kb = K + ((size_t)b * 192 + h * 48) * N;
    const int tid = threadIdx.x;
    const int ci = (tid >> 4) * 3, di = (tid & 15) * 3;
    float acc[3][3] = {};
    for (int t = 0; t < 16; t++) {
        const int n0 = nbase + t * 64;
        for (int i = 0; i < 12; i++) {
            const int idx = tid + i * 256;
            const int r = idx >> 6, cn = idx & 63;
            qs[r][cn] = Qb[(size_t)r * N + n0 + cn];
            ks[r][cn] = Kb[(size_t)r * N + n0 + cn];
        }
        __syncthreads();
        for (int n = 0; n < 64; n++) {
            float qv[3], kv[3];
            #pragma unroll
            for (int i = 0; i < 3; i++) qv[i] = qs[ci + i][n];
            #pragma unroll
            for (int j = 0; j < 3; j++) kv[j] = ks[di + j][n];
            #pragma unroll
            for (int i = 0; i < 3; i++)
                #pragma unroll
                for (int j = 0; j < 3; j++) acc[i][j] += qv[i] * kv[j];
        }
        __syncthreads();
    }
    float* A = attn_raw + ((size_t)(b * 4 + h)) * 2304;
    #pragma unroll
    for (int i = 0; i < 3; i++)
        #pragma unroll
        for (int j = 0; j < 3; j++) atomicAdd(&A[(ci + i) * 48 + di + j], acc[i][j]);
}

// ---------------- top-k(4 ways) sparsified softmax combine ----------------
__global__ __launch_bounds__(64) void topk_kernel(
    const float* __restrict__ attn_raw, const float* __restrict__ invq,
    const float* __restrict__ invk, const float* __restrict__ temp,
    const float* __restrict__ mix, float* __restrict__ Acomb)
{
    const int rowid = blockIdx.x;  // bh*48 + c
    const int c = rowid % 48, bh = rowid / 48, h = bh & 3, b = bh >> 2;
    const int lane = threadIdx.x;
    __shared__ float a[48];
    const float iq = invq[b * 192 + h * 48 + c] * temp[h];
    if (lane < 48)
        a[lane] = attn_raw[(size_t)bh * 2304 + c * 48 + lane] * iq * invk[b * 192 + h * 48 + lane];
    __syncthreads();
    const float av = (lane < 48) ? a[lane] : -INFINITY;
    int cnt_gt = 0, cnt_ge = 0;
    if (lane < 48) {
        for (int j = 0; j < 48; j++) { cnt_gt += (a[j] > av); cnt_ge += (a[j] >= av); }
    }
    const float m = wmax(av);
    const float p = (lane < 48) ? expf(av - m) : 0.f;
    float coeff = 0.f;
    const int kks[4] = {24, 32, 36, 38};
    #pragma unroll
    for (int i = 0; i < 4; i++) {
        const int kk = kks[i];
        float cand = (lane < 48 && cnt_gt < kk && cnt_ge >= kk) ? av : -INFINITY;
        cand = wmax(cand);
        const bool pass = (lane < 48) && (av >= cand);
        float z = wsum(pass ? p : 0.f);
        coeff += pass ? (mix[i] / z) : 0.f;
    }
    if (lane < 48) Acomb[(size_t)bh * 2304 + c * 48 + lane] = p * coeff;
}

// ---------------- out[c,n] = sum_d Acomb[c,d] * v[d,n] ; V is [B][192][N] ----------------
__global__ __launch_bounds__(256) void attnv_kernel(
    const float* __restrict__ Acomb, const float* __restrict__ V,
    float* __restrict__ Yout, int N)
{
    __shared__ float As[48][48];
    __shared__ float vs[48][64];
    const int b = blockIdx.z, h = blockIdx.y;
    const int n0 = blockIdx.x * 64;
    const float* Ap = Acomb + (size_t)(b * 4 + h) * 2304;
    for (int i = threadIdx.x; i < 2304; i += 256) As[i / 48][i % 48] = Ap[i];
    const float* Vb = V + ((size_t)b * 192 + h * 48) * N;
    for (int i = threadIdx.x; i < 3072; i += 256) {
        const int r = i >> 6, cn = i & 63;
        vs[r][cn] = Vb[(size_t)r * N + n0 + cn];
    }
    __syncthreads();
    const int nl = threadIdx.x & 63;
    const int cg = threadIdx.x >> 6;
    float* Yb = Yout + ((size_t)b * 192 + h * 48) * N;
    for (int c = cg * 12; c < cg * 12 + 12; c++) {
        float s = 0.f;
        #pragma unroll
        for (int d = 0; d < 48; d++) s += As[c][d] * vs[d][nl];
        Yb[(size_t)c * N + n0 + nl] = s;
    }
}

// ---------------- g = gelu_exact(A) * B, in place into A ----------------
__global__ __launch_bounds__(256) void gelumul_kernel(
    bf16* __restrict__ A, const bf16* __restrict__ Bv, size_t n)
{
    const size_t idx = (size_t)blockIdx.x * 256 + threadIdx.x;
    if (idx >= n) return;
    const float x1 = tof(A[idx]);
    const float x2 = tof(Bv[idx]);
    const float g = 0.5f * x1 * (1.f + erff(x1 * 0.70710678118654752f));
    storev(A + idx, g * x2);
}

// ---------------- launch ----------------
extern "C" void kernel_launch(void* const* d_in, const int* in_sizes, int n_in,
                              void* d_out, int out_size, void* d_ws, size_t ws_size,
                              hipStream_t stream)
{
    const float* x       = (const float*)d_in[0];
    const float* y       = (const float*)d_in[1];
    const float* ln1_w   = (const float*)d_in[2];
    const float* ln1_b   = (const float*)d_in[3];
    const float* ln2_w   = (const float*)d_in[4];
    const float* ln2_b   = (const float*)d_in[5];
    const float* kv_w    = (const float*)d_in[6];
    const float* kv_dw   = (const float*)d_in[7];
    const float* q_w     = (const float*)d_in[8];
    const float* q_dw    = (const float*)d_in[9];
    const float* po_w    = (const float*)d_in[10];
    const float* temp    = (const float*)d_in[11];
    const float* mix     = (const float*)d_in[12];
    const float* ffn_in_w  = (const float*)d_in[13];
    const float* ffn_dw    = (const float*)d_in[14];
    const float* ffn_out_w = (const float*)d_in[15];
    float* out = (float*)d_out;

    const int Bn = 4, C = 192, N = 16384, HF = 510, HC = 255;
    const size_t NP = (size_t)Bn * C * N;           // 12,582,912 elems
    const size_t CHE = (size_t)Bn * HC * N;         // chunk elems: 16,711,680

    // workspace layout (total ~144.3 MiB):
    //   [W0: NP f32][W1: NP f32][W2: NP f32][scratch 301KB]
    // FFN bf16 chunk buffers alias W0+W1 (lifetimes disjoint from fp32 uses).
    char* ws = (char*)d_ws;
    float* W0 = (float*)ws;
    float* W1 = (float*)(ws + NP * 4);
    float* W2 = (float*)(ws + NP * 8);
    bf16*  F0 = (bf16*)ws;          // fpre1 -> f2dw
    bf16*  F1 = F0 + CHE;           // fpre2
    bf16*  FD = F0 + 2 * CHE;       // f1dw -> g   (ends at 100.27MB < W2 @ 100.66MB)
    float* S  = (float*)(ws + NP * 12);
    float* invq = S;
    float* invk = S + 768;
    float* attn_raw = S + 1536;
    float* Acomb = attn_raw + 16 * 48 * 48;

    const dim3 blk(256);
    const dim3 gemm_grid3(N / 64, 3, Bn);   // O=192
    const dim3 gemm_grid4(N / 64, 4, Bn);   // O=255
    const dim3 dw_grid(N / 256, 192, Bn);
    const dim3 dwc_grid(N / 256, HC, Bn);

    // q = dw3(conv1x1(ln(y)))  -> out (scratch use of d_out)
    ln_kernel<<<dim3(Bn * N / 256), blk, 0, stream>>>(y, ln1_w, ln1_b, W0, C, N);
    conv1x1_kernel<float, float, false><<<gemm_grid3, blk, 0, stream>>>(W0, q_w, 192, nullptr, W1, 192, 192, N);
    dwconv3_kernel<float><<<dw_grid, blk, 0, stream>>>(W1, q_dw, out, 192, N);
    // xn = ln(x) -> W0 ; k -> W2 ; v -> W0 (after xn dead)
    ln_kernel<<<dim3(Bn * N / 256), blk, 0, stream>>>(x, ln1_w, ln1_b, W0, C, N);
    conv1x1_kernel<float, float, false><<<gemm_grid3, blk, 0, stream>>>(W0, kv_w, 192, nullptr, W1, 192, 192, N);
    dwconv3_kernel<float><<<dw_grid, blk, 0, stream>>>(W1, kv_dw, W2, 192, N);
    conv1x1_kernel<float, float, false><<<gemm_grid3, blk, 0, stream>>>(W0, kv_w + 192 * 192, 192, nullptr, W1, 192, 192, N);
    dwconv3_kernel<float><<<dw_grid, blk, 0, stream>>>(W1, kv_dw + 192 * 9, W0, 192, N);
    // norms + attention matrix
    rownorm_kernel<<<dim3(768), blk, 0, stream>>>(out, invq, N);
    rownorm_kernel<<<dim3(768), blk, 0, stream>>>(W2, invk, N);
    hipMemsetAsync(attn_raw, 0, 16 * 48 * 48 * 4, stream);
    gram_kernel<<<dim3(16, 4, Bn), blk, 0, stream>>>(out, W2, attn_raw, N);
    topk_kernel<<<dim3(768), dim3(64), 0, stream>>>(attn_raw, invq, invk, temp, mix, Acomb);
    // attn_out -> W1 ; x1 = x + po(attn_out) -> out
    attnv_kernel<<<dim3(N / 64, 4, Bn), blk, 0, stream>>>(Acomb, W0, W1, N);
    conv1x1_kernel<float, float, true><<<gemm_grid3, blk, 0, stream>>>(W1, po_w, 192, x, out, 192, 192, N);
    // FFN: xn2 -> W2, then 2 chunks of 255 hidden pairs, accumulate into out
    ln_kernel<<<dim3(Bn * N / 256), blk, 0, stream>>>(out, ln2_w, ln2_b, W2, C, N);
    for (int ch = 0; ch < 2; ch++) {
        conv1x1_kernel<float, bf16, false><<<gemm_grid4, blk, 0, stream>>>(W2, ffn_in_w + (size_t)(ch * HC) * 192, 192, nullptr, F0, HC, 192, N);
        conv1x1_kernel<float, bf16, false><<<gemm_grid4, blk, 0, stream>>>(W2, ffn_in_w + (size_t)(HF + ch * HC) * 192, 192, nullptr, F1, HC, 192, N);
        dwconv3_kernel<bf16><<<dwc_grid, blk, 0, stream>>>(F0, ffn_dw + (size_t)(ch * HC) * 9, FD, HC, N);
        dwconv3_kernel<bf16><<<dwc_grid, blk, 0, stream>>>(F1, ffn_dw + (size_t)(HF + ch * HC) * 9, F0, HC, N);
        gelumul_kernel<<<dim3((unsigned)((CHE + 255) / 256)), blk, 0, stream>>>(FD, F0, CHE);
        conv1x1_kernel<bf16, float, true><<<gemm_grid3, blk, 0, stream>>>(FD, ffn_out_w + ch * HC, HF, out, out, 192, HC, N);
    }
}

// Round 3
// 1755.380 us; speedup vs baseline: 1.2004x; 1.2004x over previous
//
#include <hip/hip_runtime.h>
#include <hip/hip_bf16.h>

using bf16 = __hip_bfloat16;
typedef __attribute__((ext_vector_type(8))) short short8;
typedef __attribute__((ext_vector_type(4))) float f32x4;

// ---------------- helpers ----------------
__device__ __forceinline__ float tof(float v) { return v; }
__device__ __forceinline__ float tof(bf16 v) { return __bfloat162float(v); }
__device__ __forceinline__ void storev(float* p, float v) { *p = v; }
__device__ __forceinline__ void storev(bf16* p, float v) { *p = __float2bfloat16(v); }
__device__ __forceinline__ short f2bf_bits(float v) {
    bf16 h = __float2bfloat16(v);
    return *(short*)&h;
}
__device__ __forceinline__ float wsum(float v) {
    #pragma unroll
    for (int o = 32; o > 0; o >>= 1) v += __shfl_xor(v, o);
    return v;
}
__device__ __forceinline__ float wmax(float v) {
    #pragma unroll
    for (int o = 32; o > 0; o >>= 1) v = fmaxf(v, __shfl_xor(v, o));
    return v;
}

// ---------------- LayerNorm C=192: fp32 [b][192][N] -> bf16 [b][n][192] ----------------
__global__ __launch_bounds__(256) void ln_t_kernel(
    const float* __restrict__ X, const float* __restrict__ w,
    const float* __restrict__ bias, bf16* __restrict__ Y, int N)
{
    const int wv = threadIdx.x >> 6, ln_ = threadIdx.x & 63;
    const int p = blockIdx.x * 128 + wv * 32 + (ln_ & 31);   // flat pixel in B*N
    const int b = p >> 14, n = p & 16383;                    // N = 16384
    const int c0 = (ln_ >> 5) * 96;
    const float* xp = X + ((size_t)b * 192 + c0) * N + n;
    float s = 0.f, s2 = 0.f;
    #pragma unroll
    for (int c = 0; c < 96; c++) { float v = xp[(size_t)c * N]; s += v; s2 += v * v; }
    s += __shfl_xor(s, 32);
    s2 += __shfl_xor(s2, 32);
    const float mean = s * (1.f / 192.f);
    const float rstd = rsqrtf(s2 * (1.f / 192.f) - mean * mean + 1e-5f);
    bf16* yp = Y + ((size_t)(b * 16384 + n)) * 192 + c0;
    #pragma unroll
    for (int c = 0; c < 96; c += 2) {
        float v0 = (xp[(size_t)c * N] - mean) * rstd * w[c0 + c] + bias[c0 + c];
        float v1 = (xp[(size_t)(c + 1) * N] - mean) * rstd * w[c0 + c + 1] + bias[c0 + c + 1];
        unsigned u = (unsigned)(unsigned short)f2bf_bits(v0) |
                     ((unsigned)(unsigned short)f2bf_bits(v1) << 16);
        *(unsigned*)(yp + c) = u;
    }
}

// ---------------- MFMA conv1x1: Y[b][o][n] = sum_k W[o][k] * X[b][n][k] (+Rsd) --------
template<int KPT, typename YT, bool RESID>
__global__ __launch_bounds__(256) void mfma_conv_kernel(
    const bf16* __restrict__ X, const float* __restrict__ W, int WLD,
    const float* __restrict__ Rsd, YT* __restrict__ Y,
    int O, int K, int KS, int NROW)
{
    __shared__ short Xs[64 * KPT];
    __shared__ short Ws[64 * KPT];
    const int b = blockIdx.z;
    const int n0 = blockIdx.x * 64;
    const int o0 = blockIdx.y * 64;
    const int tid = threadIdx.x;
    const int wave = tid >> 6, lane = tid & 63;
    const int KC = KPT / 8;

    f32x4 acc[4] = {{0.f,0.f,0.f,0.f},{0.f,0.f,0.f,0.f},{0.f,0.f,0.f,0.f},{0.f,0.f,0.f,0.f}};
    const bf16* Xb = X + (size_t)b * NROW * KS + (size_t)n0 * KS;

    for (int k0 = 0; k0 < K; k0 += KPT) {
        const int kt = (K - k0 < KPT) ? (K - k0) : KPT;
        for (int idx = tid; idx < 64 * KC; idx += 256) {
            const int r = idx / KC, kc = idx % KC;
            const int kbase = kc * 8;
            short8 vv = {0,0,0,0,0,0,0,0};
            if (kbase < kt) {
                const bf16* src = Xb + (size_t)r * KS + k0 + kbase;
                if (kbase + 8 <= kt) {
                    vv = *(const short8*)src;
                } else {
                    #pragma unroll
                    for (int j = 0; j < 8; j++)
                        ((short*)&vv)[j] = (kbase + j < kt) ? ((const short*)src)[j] : (short)0;
                }
            }
            *(short8*)((char*)&Xs[(size_t)r * KPT] + ((kbase * 2) ^ ((r & 7) << 4))) = vv;
        }
        for (int idx = tid; idx < 64 * KC; idx += 256) {
            const int r = idx / KC, kc = idx % KC;
            const int kbase = kc * 8;
            const int o = o0 + r;
            short8 vv = {0,0,0,0,0,0,0,0};
            if (o < O && kbase < kt) {
                const float* src = W + (size_t)o * WLD + k0 + kbase;
                #pragma unroll
                for (int j = 0; j < 8; j++)
                    ((short*)&vv)[j] = (kbase + j < kt) ? f2bf_bits(src[j]) : (short)0;
            }
            *(short8*)((char*)&Ws[(size_t)r * KPT] + ((kbase * 2) ^ ((r & 7) << 4))) = vv;
        }
        __syncthreads();
        const int arow = wave * 16 + (lane & 15);
        const int klane = (lane >> 4) * 8;
        for (int ks = 0; ks < kt; ks += 32) {
            const int akb = ks + klane;
            short8 af = *(short8*)((char*)&Ws[(size_t)arow * KPT] + ((akb * 2) ^ ((arow & 7) << 4)));
            #pragma unroll
            for (int s = 0; s < 4; s++) {
                const int brow = s * 16 + (lane & 15);
                short8 bfr = *(short8*)((char*)&Xs[(size_t)brow * KPT] + ((akb * 2) ^ ((brow & 7) << 4)));
                acc[s] = __builtin_amdgcn_mfma_f32_16x16x32_bf16(af, bfr, acc[s], 0, 0, 0);
            }
        }
        __syncthreads();
    }
    #pragma unroll
    for (int s = 0; s < 4; s++) {
        #pragma unroll
        for (int r = 0; r < 4; r++) {
            const int o = o0 + wave * 16 + (lane >> 4) * 4 + r;
            if (o < O) {
                const size_t off = ((size_t)b * O + o) * NROW + n0 + s * 16 + (lane & 15);
                float v = acc[s][r];
                if (RESID) v += Rsd[off];
                storev(&Y[off], v);
            }
        }
    }
}

// ---------------- depthwise 3x3, SAME, H=W=128 ----------------
template<typename XT, typename YT>
__global__ __launch_bounds__(256) void dwconv3_kernel(
    const XT* __restrict__ X, const float* __restrict__ Wd, YT* __restrict__ Y,
    int CH, int HW)
{
    const int pix = blockIdx.x * 256 + threadIdx.x;
    const int ch = blockIdx.y, b = blockIdx.z;
    const int py = pix >> 7, px = pix & 127;
    const size_t base = ((size_t)b * CH + ch) * HW;
    const float* w = Wd + ch * 9;
    float s = 0.f;
    #pragma unroll
    for (int dy = -1; dy <= 1; dy++) {
        const int yy = py + dy;
        if (yy < 0 || yy > 127) continue;
        #pragma unroll
        for (int dx = -1; dx <= 1; dx++) {
            const int xx = px + dx;
            if (xx < 0 || xx > 127) continue;
            s += w[(dy + 1) * 3 + (dx + 1)] * tof(X[base + yy * 128 + xx]);
        }
    }
    storev(&Y[base + pix], s);
}

// ---------------- row L2 norms (bf16 rows of length N) ----------------
__global__ __launch_bounds__(256) void rownorm_kernel(
    const bf16* __restrict__ X, float* __restrict__ inv, int N)
{
    const int row = blockIdx.x;
    const bf16* p = X + (size_t)row * N;
    float s = 0.f;
    for (int i = threadIdx.x; i < N; i += 256) { float v = tof(p[i]); s += v * v; }
    s = wsum(s);
    __shared__ float red[4];
    if ((threadIdx.x & 63) == 0) red[threadIdx.x >> 6] = s;
    __syncthreads();
    if (threadIdx.x == 0) {
        float t = red[0] + red[1] + red[2] + red[3];
        inv[row] = 1.f / fmaxf(sqrtf(t), 1e-12f);
    }
}

// ---------------- gram: attn_raw[bh,c,d] += sum_n q*k ; Q,K bf16 [B][192][N] ----------
__global__ __launch_bounds__(256) void gram_kernel(
    const bf16* __restrict__ Q, const bf16* __restrict__ K,
    float* __restrict__ attn_raw, int N)
{
    __shared__ float qs[48][65];
    __shared__ float ks[48][65];
    const int b = blockIdx.z, h = blockIdx.y;
    const int nbase = blockIdx.x * 1024;
    const bf16* Qb = Q + ((size_t)b * 192 + h * 48) * N;
    const bf16* Kb = K + ((size_t)b * 192 + h * 48) * N;
    const int tid = threadIdx.x;
    const int ci = (tid >> 4) * 3, di = (tid & 15) * 3;
    float acc[3][3] = {};
    for (int t = 0; t < 16; t++) {
        const int n0 = nbase + t * 64;
        for (int i = 0; i < 12; i++) {
            const int idx = tid + i * 256;
            const int r = idx >> 6, cn = idx & 63;
            qs[r][cn] = tof(Qb[(size_t)r * N + n0 + cn]);
            ks[r][cn] = tof(Kb[(size_t)r * N + n0 + cn]);
        }
        __syncthreads();
        for (int n = 0; n < 64; n++) {
            float qv[3], kv[3];
            #pragma unroll
            for (int i = 0; i < 3; i++) qv[i] = qs[ci + i][n];
            #pragma unroll
            for (int j = 0; j < 3; j++) kv[j] = ks[di + j][n];
            #pragma unroll
            for (int i = 0; i < 3; i++)
                #pragma unroll
                for (int j = 0; j < 3; j++) acc[i][j] += qv[i] * kv[j];
        }
        __syncthreads();
    }
    float* A = attn_raw + ((size_t)(b * 4 + h)) * 2304;
    #pragma unroll
    for (int i = 0; i < 3; i++)
        #pragma unroll
        for (int j = 0; j < 3; j++) atomicAdd(&A[(ci + i) * 48 + di + j], acc[i][j]);
}

// ---------------- top-k(4 ways) sparsified softmax combine ----------------
__global__ __launch_bounds__(64) void topk_kernel(
    const float* __restrict__ attn_raw, const float* __restrict__ invq,
    const float* __restrict__ invk, const float* __restrict__ temp,
    const float* __restrict__ mix, float* __restrict__ Acomb)
{
    const int rowid = blockIdx.x;  // bh*48 + c
    const int c = rowid % 48, bh = rowid / 48, h = bh & 3, b = bh >> 2;
    const int lane = threadIdx.x;
    __shared__ float a[48];
    const float iq = invq[b * 192 + h * 48 + c] * temp[h];
    if (lane < 48)
        a[lane] = attn_raw[(size_t)bh * 2304 + c * 48 + lane] * iq * invk[b * 192 + h * 48 + lane];
    __syncthreads();
    const float av = (lane < 48) ? a[lane] : -INFINITY;
    int cnt_gt = 0, cnt_ge = 0;
    if (lane < 48) {
        for (int j = 0; j < 48; j++) { cnt_gt += (a[j] > av); cnt_ge += (a[j] >= av); }
    }
    const float m = wmax(av);
    const float p = (lane < 48) ? expf(av - m) : 0.f;
    float coeff = 0.f;
    const int kks[4] = {24, 32, 36, 38};
    #pragma unroll
    for (int i = 0; i < 4; i++) {
        const int kk = kks[i];
        float cand = (lane < 48 && cnt_gt < kk && cnt_ge >= kk) ? av : -INFINITY;
        cand = wmax(cand);
        const bool pass = (lane < 48) && (av >= cand);
        float z = wsum(pass ? p : 0.f);
        coeff += pass ? (mix[i] / z) : 0.f;
    }
    if (lane < 48) Acomb[(size_t)bh * 2304 + c * 48 + lane] = p * coeff;
}

// ---------------- attn_out (T-layout bf16 [b][n][192]) = Acomb @ v ----------------
__global__ __launch_bounds__(256) void attnv_kernel(
    const float* __restrict__ Acomb, const bf16* __restrict__ V,
    bf16* __restrict__ OT, int N)
{
    __shared__ float As[48][48];
    __shared__ float vs[48][64];
    __shared__ bf16 ot[64][48];
    const int b = blockIdx.z, h = blockIdx.y;
    const int n0 = blockIdx.x * 64;
    const float* Ap = Acomb + (size_t)(b * 4 + h) * 2304;
    for (int i = threadIdx.x; i < 2304; i += 256) As[i / 48][i % 48] = Ap[i];
    const bf16* Vb = V + ((size_t)b * 192 + h * 48) * N;
    for (int i = threadIdx.x; i < 3072; i += 256) {
        const int r = i >> 6, cn = i & 63;
        vs[r][cn] = tof(Vb[(size_t)r * N + n0 + cn]);
    }
    __syncthreads();
    const int nl = threadIdx.x & 63;
    const int cg = threadIdx.x >> 6;
    for (int c = cg * 12; c < cg * 12 + 12; c++) {
        float s = 0.f;
        #pragma unroll
        for (int d = 0; d < 48; d++) s += As[c][d] * vs[d][nl];
        ot[nl][c] = __float2bfloat16(s);
    }
    __syncthreads();
    for (int idx = threadIdx.x; idx < 384; idx += 256) {
        const int r = idx / 6, q = idx % 6;
        *(uint4*)((char*)&OT[((size_t)b * N + n0 + r) * 192 + h * 48] + q * 16) =
            *(uint4*)((char*)&ot[r][0] + q * 16);
    }
}

// ------ fused dw3(f1)->gelu * dw3(f2), transposed write -> gT[b][n][512] (pad cols 0) --
__global__ __launch_bounds__(256) void dwgelu_t_kernel(
    const bf16* __restrict__ F1, const bf16* __restrict__ F2,
    const float* __restrict__ Wd, bf16* __restrict__ GT, int N)
{
    __shared__ bf16 ot[64][16];
    const int b = blockIdx.z;
    const int n0 = blockIdx.x * 64;
    const int hc0 = blockIdx.y * 16;
    const int tid = threadIdx.x;
    const int nl = tid & 63, hg = tid >> 6;
    const int n = n0 + nl;
    const int py = n >> 7, px = n & 127;
    #pragma unroll
    for (int i = 0; i < 4; i++) {
        const int hcl = hg * 4 + i;
        const int hc = hc0 + hcl;
        float val = 0.f;
        if (hc < 510) {
            const size_t base1 = ((size_t)b * 510 + hc) * N;
            const size_t base2 = ((size_t)(b * 510) + 510 * 2 * 0 + hc) * N; // F2 indexed separately
            const float* w1 = Wd + (size_t)hc * 9;
            const float* w2 = Wd + (size_t)(510 + hc) * 9;
            float d1 = 0.f, d2 = 0.f;
            #pragma unroll
            for (int dy = -1; dy <= 1; dy++) {
                const int yy = py + dy;
                if (yy < 0 || yy > 127) continue;
                #pragma unroll
                for (int dx = -1; dx <= 1; dx++) {
                    const int xx = px + dx;
                    if (xx < 0 || xx > 127) continue;
                    const size_t sp = (size_t)yy * 128 + xx;
                    const float ww1 = w1[(dy + 1) * 3 + (dx + 1)];
                    const float ww2 = w2[(dy + 1) * 3 + (dx + 1)];
                    d1 += ww1 * tof(F1[base1 + sp]);
                    d2 += ww2 * tof(F2[base2 + sp]);
                }
            }
            const float g = 0.5f * d1 * (1.f + erff(d1 * 0.70710678118654752f));
            val = g * d2;
        }
        ot[nl][hcl] = __float2bfloat16(val);
    }
    __syncthreads();
    const int r = tid >> 2, q = tid & 3;
    *(uint2*)((char*)&GT[((size_t)b * N + n0 + r) * 512 + hc0] + q * 8) =
        *(uint2*)((char*)&ot[r][0] + q * 8);
}

// ---------------- launch ----------------
extern "C" void kernel_launch(void* const* d_in, const int* in_sizes, int n_in,
                              void* d_out, int out_size, void* d_ws, size_t ws_size,
                              hipStream_t stream)
{
    const float* x       = (const float*)d_in[0];
    const float* y       = (const float*)d_in[1];
    const float* ln1_w   = (const float*)d_in[2];
    const float* ln1_b   = (const float*)d_in[3];
    const float* ln2_w   = (const float*)d_in[4];
    const float* ln2_b   = (const float*)d_in[5];
    const float* kv_w    = (const float*)d_in[6];
    const float* kv_dw   = (const float*)d_in[7];
    const float* q_w     = (const float*)d_in[8];
    const float* q_dw    = (const float*)d_in[9];
    const float* po_w    = (const float*)d_in[10];
    const float* temp    = (const float*)d_in[11];
    const float* mix     = (const float*)d_in[12];
    const float* ffn_in_w  = (const float*)d_in[13];
    const float* ffn_dw    = (const float*)d_in[14];
    const float* ffn_out_w = (const float*)d_in[15];
    float* out = (float*)d_out;

    const int N = 16384;
    const size_t TB = (size_t)4 * N * 192 * 2;   // 25,165,824 bytes (one bf16 [4][*][*] act)

    char* ws = (char*)d_ws;
    bf16* XT0 = (bf16*)ws;                        // yn / xn / xn2 (T-layout)
    bf16* XT1 = (bf16*)(ws + TB);                 // q/k/v_pre ([o][n]) then attn_outT
    bf16* Q   = (bf16*)(ws + 2 * TB);
    bf16* Kb  = (bf16*)(ws + 3 * TB);
    bf16* V   = (bf16*)(ws + 4 * TB);
    float* S  = (float*)(ws + 5 * TB);            // @ 125,829,120
    float* invq = S;
    float* invk = S + 768;
    float* attn_raw = S + 1536;
    float* Acomb = attn_raw + 16 * 48 * 48;
    // FFN overlay (attention buffers dead): F1 @ TB, F2, GT
    bf16* F1 = (bf16*)(ws + TB);                          // 2*510*N*2 = 33,423,360
    bf16* F2 = (bf16*)(ws + TB + 33423360);
    bf16* GT = (bf16*)(ws + TB + 2 * (size_t)33423360);   // 2*N*512*2 = 33,554,432 -> ends 125,566,976

    const dim3 blk(256);
    const dim3 ln_grid(4 * N / 128);
    const dim3 g192(N / 64, 3, 4);
    const dim3 dwg(N / 256, 192, 4);

    // q path
    ln_t_kernel<<<ln_grid, blk, 0, stream>>>(y, ln1_w, ln1_b, XT0, N);
    mfma_conv_kernel<192, bf16, false><<<g192, blk, 0, stream>>>(XT0, q_w, 192, nullptr, XT1, 192, 192, 192, N);
    dwconv3_kernel<bf16, bf16><<<dwg, blk, 0, stream>>>(XT1, q_dw, Q, 192, N);
    // k, v path
    ln_t_kernel<<<ln_grid, blk, 0, stream>>>(x, ln1_w, ln1_b, XT0, N);
    mfma_conv_kernel<192, bf16, false><<<g192, blk, 0, stream>>>(XT0, kv_w, 192, nullptr, XT1, 192, 192, 192, N);
    dwconv3_kernel<bf16, bf16><<<dwg, blk, 0, stream>>>(XT1, kv_dw, Kb, 192, N);
    mfma_conv_kernel<192, bf16, false><<<g192, blk, 0, stream>>>(XT0, kv_w + 192 * 192, 192, nullptr, XT1, 192, 192, 192, N);
    dwconv3_kernel<bf16, bf16><<<dwg, blk, 0, stream>>>(XT1, kv_dw + 192 * 9, V, 192, N);
    // norms, attention matrix, combine
    rownorm_kernel<<<dim3(768), blk, 0, stream>>>(Q, invq, N);
    rownorm_kernel<<<dim3(768), blk, 0, stream>>>(Kb, invk, N);
    hipMemsetAsync(attn_raw, 0, 16 * 48 * 48 * 4, stream);
    gram_kernel<<<dim3(16, 4, 4), blk, 0, stream>>>(Q, Kb, attn_raw, N);
    topk_kernel<<<dim3(768), dim3(64), 0, stream>>>(attn_raw, invq, invk, temp, mix, Acomb);
    // attn_out (T) -> XT1 ; x1 = x + po(attn_out) -> out
    attnv_kernel<<<dim3(N / 64, 4, 4), blk, 0, stream>>>(Acomb, V, XT1, N);
    mfma_conv_kernel<192, float, true><<<g192, blk, 0, stream>>>(XT1, po_w, 192, x, out, 192, 192, 192, N);
    // FFN
    ln_t_kernel<<<ln_grid, blk, 0, stream>>>(out, ln2_w, ln2_b, XT0, N);
    for (int bp = 0; bp < 2; bp++) {
        const bf16* X2 = XT0 + (size_t)bp * 2 * N * 192;
        float* Ybp = out + (size_t)bp * 2 * 192 * N;
        mfma_conv_kernel<192, bf16, false><<<dim3(N / 64, 8, 2), blk, 0, stream>>>(X2, ffn_in_w, 192, nullptr, F1, 510, 192, 192, N);
        mfma_conv_kernel<192, bf16, false><<<dim3(N / 64, 8, 2), blk, 0, stream>>>(X2, ffn_in_w + (size_t)510 * 192, 192, nullptr, F2, 510, 192, 192, N);
        dwgelu_t_kernel<<<dim3(N / 64, 32, 2), blk, 0, stream>>>(F1, F2, ffn_dw, GT, N);
        mfma_conv_kernel<256, float, true><<<dim3(N / 64, 3, 2), blk, 0, stream>>>(GT, ffn_out_w, 510, Ybp, Ybp, 192, 510, 512, N);
    }
}

// Round 4
// 1217.011 us; speedup vs baseline: 1.7314x; 1.4424x over previous
//
#include <hip/hip_runtime.h>
#include <hip/hip_bf16.h>

using bf16 = __hip_bfloat16;
typedef __attribute__((ext_vector_type(8))) short short8;
typedef __attribute__((ext_vector_type(4))) float f32x4;

// ---------------- helpers ----------------
__device__ __forceinline__ float tof(float v) { return v; }
__device__ __forceinline__ float tof(bf16 v) { return __bfloat162float(v); }
__device__ __forceinline__ void storev(float* p, float v) { *p = v; }
__device__ __forceinline__ void storev(bf16* p, float v) { *p = __float2bfloat16(v); }
__device__ __forceinline__ short f2bf_bits(float v) {
    bf16 h = __float2bfloat16(v);
    return *(short*)&h;
}
__device__ __forceinline__ float wsum(float v) {
    #pragma unroll
    for (int o = 32; o > 0; o >>= 1) v += __shfl_xor(v, o);
    return v;
}
__device__ __forceinline__ float wmax(float v) {
    #pragma unroll
    for (int o = 32; o > 0; o >>= 1) v = fmaxf(v, __shfl_xor(v, o));
    return v;
}

// ---------------- weight preconvert: fp32 [Oreal][WLD] -> bf16 [Oalloc][KP], pad 0 ----
__global__ __launch_bounds__(256) void wconv_kernel(
    const float* __restrict__ src, bf16* __restrict__ dst,
    int Oreal, int Oalloc, int K, int KP, int WLD)
{
    const int idx = blockIdx.x * 256 + threadIdx.x;
    if (idx >= Oalloc * KP) return;
    const int o = idx / KP, k = idx % KP;
    float v = (o < Oreal && k < K) ? src[(size_t)o * WLD + k] : 0.f;
    dst[idx] = __float2bfloat16(v);
}

// ---------------- LayerNorm C=192: fp32 [b][192][N] -> bf16 [b][n][192] ----------------
__global__ __launch_bounds__(256) void ln_t_kernel(
    const float* __restrict__ X, const float* __restrict__ w,
    const float* __restrict__ bias, bf16* __restrict__ Y, int N)
{
    const int wv = threadIdx.x >> 6, ln_ = threadIdx.x & 63;
    const int p = blockIdx.x * 128 + wv * 32 + (ln_ & 31);   // flat pixel in B*N
    const int b = p >> 14, n = p & 16383;                    // N = 16384
    const int c0 = (ln_ >> 5) * 96;
    const float* xp = X + ((size_t)b * 192 + c0) * N + n;
    float s = 0.f, s2 = 0.f;
    #pragma unroll
    for (int c = 0; c < 96; c++) { float v = xp[(size_t)c * N]; s += v; s2 += v * v; }
    s += __shfl_xor(s, 32);
    s2 += __shfl_xor(s2, 32);
    const float mean = s * (1.f / 192.f);
    const float rstd = rsqrtf(s2 * (1.f / 192.f) - mean * mean + 1e-5f);
    bf16* yp = Y + ((size_t)(b * 16384 + n)) * 192 + c0;
    #pragma unroll
    for (int c = 0; c < 96; c += 2) {
        float v0 = (xp[(size_t)c * N] - mean) * rstd * w[c0 + c] + bias[c0 + c];
        float v1 = (xp[(size_t)(c + 1) * N] - mean) * rstd * w[c0 + c + 1] + bias[c0 + c + 1];
        unsigned u = (unsigned)(unsigned short)f2bf_bits(v0) |
                     ((unsigned)(unsigned short)f2bf_bits(v1) << 16);
        *(unsigned*)(yp + c) = u;
    }
}

// ---- weights-in-registers MFMA GEMM: Y[b][o][n] = sum_k Wb[o][k] * X[b][n][k] (+Rsd) --
// Wb bf16 [>=o0+64][K] (rows beyond real O zero/readable). X bf16 [B][NROW][KS].
// Block: 4 waves; wave w owns o rows [o0+16w, +16). No LDS, no barriers.
template<int K, typename YT, bool RESID>
__global__ __launch_bounds__(256) void wreg_gemm_kernel(
    const bf16* __restrict__ Wb, const bf16* __restrict__ X,
    const float* __restrict__ Rsd, YT* __restrict__ Y,
    int O, int KS, int NROW, int NSTEP)
{
    constexpr int KST = K / 32;
    const int b = blockIdx.z;
    const int o0 = blockIdx.x * 64;
    const int nbase = blockIdx.y * NSTEP;
    const int wave = threadIdx.x >> 6, lane = threadIdx.x & 63;
    const int arow = lane & 15, kg = lane >> 4;

    short8 wf[KST];
    {
        const bf16* wp = Wb + (size_t)(o0 + wave * 16 + arow) * K + kg * 8;
        #pragma unroll
        for (int ks = 0; ks < KST; ks++) wf[ks] = *(const short8*)(wp + ks * 32);
    }
    const bf16* Xb = X + ((size_t)b * NROW + nbase) * KS;

    for (int nt = 0; nt < NSTEP; nt += 64) {
        f32x4 acc[4];
        #pragma unroll
        for (int s = 0; s < 4; s++) acc[s] = (f32x4){0.f, 0.f, 0.f, 0.f};
        #pragma unroll
        for (int s = 0; s < 4; s++) {
            const bf16* xp = Xb + (size_t)(nt + s * 16 + arow) * KS + kg * 8;
            #pragma unroll
            for (int ks = 0; ks < KST; ks++) {
                short8 bfr = *(const short8*)(xp + ks * 32);
                acc[s] = __builtin_amdgcn_mfma_f32_16x16x32_bf16(wf[ks], bfr, acc[s], 0, 0, 0);
            }
        }
        #pragma unroll
        for (int s = 0; s < 4; s++) {
            #pragma unroll
            for (int r = 0; r < 4; r++) {
                const int o = o0 + wave * 16 + kg * 4 + r;
                if (o < O) {
                    const size_t off = ((size_t)b * O + o) * NROW + nbase + nt + s * 16 + arow;
                    float v = acc[s][r];
                    if (RESID) v += Rsd[off];
                    storev(&Y[off], v);
                }
            }
        }
    }
}

// ---------------- depthwise 3x3, SAME, H=W=128 ----------------
template<typename XT, typename YT>
__global__ __launch_bounds__(256) void dwconv3_kernel(
    const XT* __restrict__ X, const float* __restrict__ Wd, YT* __restrict__ Y,
    int CH, int HW)
{
    const int pix = blockIdx.x * 256 + threadIdx.x;
    const int ch = blockIdx.y, b = blockIdx.z;
    const int py = pix >> 7, px = pix & 127;
    const size_t base = ((size_t)b * CH + ch) * HW;
    const float* w = Wd + ch * 9;
    float s = 0.f;
    #pragma unroll
    for (int dy = -1; dy <= 1; dy++) {
        const int yy = py + dy;
        if (yy < 0 || yy > 127) continue;
        #pragma unroll
        for (int dx = -1; dx <= 1; dx++) {
            const int xx = px + dx;
            if (xx < 0 || xx > 127) continue;
            s += w[(dy + 1) * 3 + (dx + 1)] * tof(X[base + yy * 128 + xx]);
        }
    }
    storev(&Y[base + pix], s);
}

// ---------------- row L2 norms (bf16 rows of length N) ----------------
__global__ __launch_bounds__(256) void rownorm_kernel(
    const bf16* __restrict__ X, float* __restrict__ inv, int N)
{
    const int row = blockIdx.x;
    const bf16* p = X + (size_t)row * N;
    float s = 0.f;
    for (int i = threadIdx.x; i < N; i += 256) { float v = tof(p[i]); s += v * v; }
    s = wsum(s);
    __shared__ float red[4];
    if ((threadIdx.x & 63) == 0) red[threadIdx.x >> 6] = s;
    __syncthreads();
    if (threadIdx.x == 0) {
        float t = red[0] + red[1] + red[2] + red[3];
        inv[row] = 1.f / fmaxf(sqrtf(t), 1e-12f);
    }
}

// ---------------- gram: attn_raw[bh,c,d] += sum_n q*k ; Q,K bf16 [B][192][N] ----------
__global__ __launch_bounds__(256) void gram_kernel(
    const bf16* __restrict__ Q, const bf16* __restrict__ K,
    float* __restrict__ attn_raw, int N)
{
    __shared__ float qs[48][65];
    __shared__ float ks[48][65];
    const int b = blockIdx.z, h = blockIdx.y;
    const int nbase = blockIdx.x * 1024;
    const bf16* Qb = Q + ((size_t)b * 192 + h * 48) * N;
    const bf16* Kb = K + ((size_t)b * 192 + h * 48) * N;
    const int tid = threadIdx.x;
    const int ci = (tid >> 4) * 3, di = (tid & 15) * 3;
    float acc[3][3] = {};
    for (int t = 0; t < 16; t++) {
        const int n0 = nbase + t * 64;
        for (int i = 0; i < 12; i++) {
            const int idx = tid + i * 256;
            const int r = idx >> 6, cn = idx & 63;
            qs[r][cn] = tof(Qb[(size_t)r * N + n0 + cn]);
            ks[r][cn] = tof(Kb[(size_t)r * N + n0 + cn]);
        }
        __syncthreads();
        for (int n = 0; n < 64; n++) {
            float qv[3], kv[3];
            #pragma unroll
            for (int i = 0; i < 3; i++) qv[i] = qs[ci + i][n];
            #pragma unroll
            for (int j = 0; j < 3; j++) kv[j] = ks[di + j][n];
            #pragma unroll
            for (int i = 0; i < 3; i++)
                #pragma unroll
                for (int j = 0; j < 3; j++) acc[i][j] += qv[i] * kv[j];
        }
        __syncthreads();
    }
    float* A = attn_raw + ((size_t)(b * 4 + h)) * 2304;
    #pragma unroll
    for (int i = 0; i < 3; i++)
        #pragma unroll
        for (int j = 0; j < 3; j++) atomicAdd(&A[(ci + i) * 48 + di + j], acc[i][j]);
}

// ---------------- top-k(4 ways) sparsified softmax combine ----------------
__global__ __launch_bounds__(64) void topk_kernel(
    const float* __restrict__ attn_raw, const float* __restrict__ invq,
    const float* __restrict__ invk, const float* __restrict__ temp,
    const float* __restrict__ mix, float* __restrict__ Acomb)
{
    const int rowid = blockIdx.x;  // bh*48 + c
    const int c = rowid % 48, bh = rowid / 48, h = bh & 3, b = bh >> 2;
    const int lane = threadIdx.x;
    __shared__ float a[48];
    const float iq = invq[b * 192 + h * 48 + c] * temp[h];
    if (lane < 48)
        a[lane] = attn_raw[(size_t)bh * 2304 + c * 48 + lane] * iq * invk[b * 192 + h * 48 + lane];
    __syncthreads();
    const float av = (lane < 48) ? a[lane] : -INFINITY;
    int cnt_gt = 0, cnt_ge = 0;
    if (lane < 48) {
        for (int j = 0; j < 48; j++) { cnt_gt += (a[j] > av); cnt_ge += (a[j] >= av); }
    }
    const float m = wmax(av);
    const float p = (lane < 48) ? expf(av - m) : 0.f;
    float coeff = 0.f;
    const int kks[4] = {24, 32, 36, 38};
    #pragma unroll
    for (int i = 0; i < 4; i++) {
        const int kk = kks[i];
        float cand = (lane < 48 && cnt_gt < kk && cnt_ge >= kk) ? av : -INFINITY;
        cand = wmax(cand);
        const bool pass = (lane < 48) && (av >= cand);
        float z = wsum(pass ? p : 0.f);
        coeff += pass ? (mix[i] / z) : 0.f;
    }
    if (lane < 48) Acomb[(size_t)bh * 2304 + c * 48 + lane] = p * coeff;
}

// ---------------- attn_out (T-layout bf16 [b][n][192]) = Acomb @ v ----------------
__global__ __launch_bounds__(256) void attnv_kernel(
    const float* __restrict__ Acomb, const bf16* __restrict__ V,
    bf16* __restrict__ OT, int N)
{
    __shared__ float As[48][48];
    __shared__ float vs[48][64];
    __shared__ bf16 ot[64][48];
    const int b = blockIdx.z, h = blockIdx.y;
    const int n0 = blockIdx.x * 64;
    const float* Ap = Acomb + (size_t)(b * 4 + h) * 2304;
    for (int i = threadIdx.x; i < 2304; i += 256) As[i / 48][i % 48] = Ap[i];
    const bf16* Vb = V + ((size_t)b * 192 + h * 48) * N;
    for (int i = threadIdx.x; i < 3072; i += 256) {
        const int r = i >> 6, cn = i & 63;
        vs[r][cn] = tof(Vb[(size_t)r * N + n0 + cn]);
    }
    __syncthreads();
    const int nl = threadIdx.x & 63;
    const int cg = threadIdx.x >> 6;
    for (int c = cg * 12; c < cg * 12 + 12; c++) {
        float s = 0.f;
        #pragma unroll
        for (int d = 0; d < 48; d++) s += As[c][d] * vs[d][nl];
        ot[nl][c] = __float2bfloat16(s);
    }
    __syncthreads();
    for (int idx = threadIdx.x; idx < 384; idx += 256) {
        const int r = idx / 6, q = idx % 6;
        *(uint4*)((char*)&OT[((size_t)b * N + n0 + r) * 192 + h * 48] + q * 16) =
            *(uint4*)((char*)&ot[r][0] + q * 16);
    }
}

// ------ fused dw3(f1)->gelu * dw3(f2), transposed write -> gT[b][n][512] (pad cols 0) --
__global__ __launch_bounds__(256) void dwgelu_t_kernel(
    const bf16* __restrict__ F1, const bf16* __restrict__ F2,
    const float* __restrict__ Wd, bf16* __restrict__ GT, int N)
{
    __shared__ bf16 ot[64][16];
    const int b = blockIdx.z;
    const int n0 = blockIdx.x * 64;
    const int hc0 = blockIdx.y * 16;
    const int tid = threadIdx.x;
    const int nl = tid & 63, hg = tid >> 6;
    const int n = n0 + nl;
    const int py = n >> 7, px = n & 127;
    #pragma unroll
    for (int i = 0; i < 4; i++) {
        const int hcl = hg * 4 + i;
        const int hc = hc0 + hcl;
        float val = 0.f;
        if (hc < 510) {
            const size_t base1 = ((size_t)b * 510 + hc) * N;
            const size_t base2 = ((size_t)b * 510 + hc) * N;
            const float* w1 = Wd + (size_t)hc * 9;
            const float* w2 = Wd + (size_t)(510 + hc) * 9;
            float d1 = 0.f, d2 = 0.f;
            #pragma unroll
            for (int dy = -1; dy <= 1; dy++) {
                const int yy = py + dy;
                if (yy < 0 || yy > 127) continue;
                #pragma unroll
                for (int dx = -1; dx <= 1; dx++) {
                    const int xx = px + dx;
                    if (xx < 0 || xx > 127) continue;
                    const size_t sp = (size_t)yy * 128 + xx;
                    d1 += w1[(dy + 1) * 3 + (dx + 1)] * tof(F1[base1 + sp]);
                    d2 += w2[(dy + 1) * 3 + (dx + 1)] * tof(F2[base2 + sp]);
                }
            }
            const float g = 0.5f * d1 * (1.f + erff(d1 * 0.70710678118654752f));
            val = g * d2;
        }
        ot[nl][hcl] = __float2bfloat16(val);
    }
    __syncthreads();
    const int r = tid >> 2, q = tid & 3;
    *(uint2*)((char*)&GT[((size_t)b * N + n0 + r) * 512 + hc0] + q * 8) =
        *(uint2*)((char*)&ot[r][0] + q * 8);
}

// ---------------- launch ----------------
extern "C" void kernel_launch(void* const* d_in, const int* in_sizes, int n_in,
                              void* d_out, int out_size, void* d_ws, size_t ws_size,
                              hipStream_t stream)
{
    const float* x       = (const float*)d_in[0];
    const float* y       = (const float*)d_in[1];
    const float* ln1_w   = (const float*)d_in[2];
    const float* ln1_b   = (const float*)d_in[3];
    const float* ln2_w   = (const float*)d_in[4];
    const float* ln2_b   = (const float*)d_in[5];
    const float* kv_w    = (const float*)d_in[6];
    const float* kv_dw   = (const float*)d_in[7];
    const float* q_w     = (const float*)d_in[8];
    const float* q_dw    = (const float*)d_in[9];
    const float* po_w    = (const float*)d_in[10];
    const float* temp    = (const float*)d_in[11];
    const float* mix     = (const float*)d_in[12];
    const float* ffn_in_w  = (const float*)d_in[13];
    const float* ffn_dw    = (const float*)d_in[14];
    const float* ffn_out_w = (const float*)d_in[15];
    float* out = (float*)d_out;

    const int N = 16384;
    const size_t TB = (size_t)4 * N * 192 * 2;   // 25,165,824 bytes

    char* ws = (char*)d_ws;
    bf16* XT0 = (bf16*)ws;                        // yn / xn / xn2 (T-layout)
    bf16* XT1 = (bf16*)(ws + TB);                 // q/k/v_pre then attn_outT
    bf16* Q   = (bf16*)(ws + 2 * TB);
    bf16* Kb  = (bf16*)(ws + 3 * TB);
    bf16* V   = (bf16*)(ws + 4 * TB);
    float* S  = (float*)(ws + 5 * TB);            // @ 125,829,120
    float* invq = S;
    float* invk = S + 768;
    float* attn_raw = S + 1536;
    float* Acomb = attn_raw + 16 * 48 * 48;       // S region < 310 KB
    // bf16 weights after S region
    bf16* Wq  = (bf16*)(ws + 5 * TB + 331776);
    bf16* Wkv = Wq + 36864;        // 384x192
    bf16* Wpo = Wkv + 73728;       // 192x192
    bf16* Wfi = Wpo + 36864;       // 1024x192 (1020 real + 4 zero rows)
    bf16* Wfo = Wfi + 196608;      // 192x512  (K padded 510->512)
    // FFN overlay (attention buffers dead): F1/F2/GT over XT1..V
    bf16* F1 = (bf16*)(ws + TB);                          // [2][510][N]
    bf16* F2 = (bf16*)(ws + TB + (size_t)33423360);
    bf16* GT = (bf16*)(ws + TB + 2 * (size_t)33423360);   // [2][N][512]

    const dim3 blk(256);
    const dim3 ln_grid(4 * N / 128);
    const dim3 dwg(N / 256, 192, 4);

    // ---- preconvert weights to bf16 ----
    wconv_kernel<<<dim3((192 * 192 + 255) / 256), blk, 0, stream>>>(q_w, Wq, 192, 192, 192, 192, 192);
    wconv_kernel<<<dim3((384 * 192 + 255) / 256), blk, 0, stream>>>(kv_w, Wkv, 384, 384, 192, 192, 192);
    wconv_kernel<<<dim3((192 * 192 + 255) / 256), blk, 0, stream>>>(po_w, Wpo, 192, 192, 192, 192, 192);
    wconv_kernel<<<dim3((1024 * 192 + 255) / 256), blk, 0, stream>>>(ffn_in_w, Wfi, 1020, 1024, 192, 192, 192);
    wconv_kernel<<<dim3((192 * 512 + 255) / 256), blk, 0, stream>>>(ffn_out_w, Wfo, 192, 192, 510, 512, 510);

    // ---- q path ----
    ln_t_kernel<<<ln_grid, blk, 0, stream>>>(y, ln1_w, ln1_b, XT0, N);
    wreg_gemm_kernel<192, bf16, false><<<dim3(3, N / 128, 4), blk, 0, stream>>>(Wq, XT0, nullptr, XT1, 192, 192, N, 128);
    dwconv3_kernel<bf16, bf16><<<dwg, blk, 0, stream>>>(XT1, q_dw, Q, 192, N);
    // ---- k, v path ----
    ln_t_kernel<<<ln_grid, blk, 0, stream>>>(x, ln1_w, ln1_b, XT0, N);
    wreg_gemm_kernel<192, bf16, false><<<dim3(3, N / 128, 4), blk, 0, stream>>>(Wkv, XT0, nullptr, XT1, 192, 192, N, 128);
    dwconv3_kernel<bf16, bf16><<<dwg, blk, 0, stream>>>(XT1, kv_dw, Kb, 192, N);
    wreg_gemm_kernel<192, bf16, false><<<dim3(3, N / 128, 4), blk, 0, stream>>>(Wkv + 192 * 192, XT0, nullptr, XT1, 192, 192, N, 128);
    dwconv3_kernel<bf16, bf16><<<dwg, blk, 0, stream>>>(XT1, kv_dw + 192 * 9, V, 192, N);
    // ---- norms, attention matrix, combine ----
    rownorm_kernel<<<dim3(768), blk, 0, stream>>>(Q, invq, N);
    rownorm_kernel<<<dim3(768), blk, 0, stream>>>(Kb, invk, N);
    hipMemsetAsync(attn_raw, 0, 16 * 48 * 48 * 4, stream);
    gram_kernel<<<dim3(16, 4, 4), blk, 0, stream>>>(Q, Kb, attn_raw, N);
    topk_kernel<<<dim3(768), dim3(64), 0, stream>>>(attn_raw, invq, invk, temp, mix, Acomb);
    // ---- attn_out (T) -> XT1 ; x1 = x + po(attn_out) -> out ----
    attnv_kernel<<<dim3(N / 64, 4, 4), blk, 0, stream>>>(Acomb, V, XT1, N);
    wreg_gemm_kernel<192, float, true><<<dim3(3, N / 128, 4), blk, 0, stream>>>(Wpo, XT1, x, out, 192, 192, N, 128);
    // ---- FFN ----
    ln_t_kernel<<<ln_grid, blk, 0, stream>>>(out, ln2_w, ln2_b, XT0, N);
    for (int bp = 0; bp < 2; bp++) {
        const bf16* X2 = XT0 + (size_t)bp * 2 * N * 192;
        float* Ybp = out + (size_t)bp * 2 * 192 * N;
        wreg_gemm_kernel<192, bf16, false><<<dim3(8, N / 256, 2), blk, 0, stream>>>(Wfi, X2, nullptr, F1, 510, 192, N, 256);
        wreg_gemm_kernel<192, bf16, false><<<dim3(8, N / 256, 2), blk, 0, stream>>>(Wfi + (size_t)510 * 192, X2, nullptr, F2, 510, 192, N, 256);
        dwgelu_t_kernel<<<dim3(N / 64, 32, 2), blk, 0, stream>>>(F1, F2, ffn_dw, GT, N);
        wreg_gemm_kernel<512, float, true><<<dim3(3, N / 128, 2), blk, 0, stream>>>(Wfo, GT, Ybp, Ybp, 192, 512, N, 128);
    }
}

// Round 7
// 1004.657 us; speedup vs baseline: 2.0974x; 1.2114x over previous
//
#include <hip/hip_runtime.h>
#include <hip/hip_bf16.h>

using bf16 = __hip_bfloat16;
typedef __attribute__((ext_vector_type(8))) short short8;
typedef __attribute__((ext_vector_type(4))) float f32x4;

// ---------------- helpers ----------------
__device__ __forceinline__ float tof(float v) { return v; }
__device__ __forceinline__ float tof(bf16 v) { return __bfloat162float(v); }
__device__ __forceinline__ float s2f(short s) {
    return __uint_as_float(((unsigned)(unsigned short)s) << 16);
}
__device__ __forceinline__ void storev(float* p, float v) { *p = v; }
__device__ __forceinline__ void storev(bf16* p, float v) { *p = __float2bfloat16(v); }
__device__ __forceinline__ short f2bf_bits(float v) {
    bf16 h = __float2bfloat16(v);
    return *(short*)&h;
}
__device__ __forceinline__ float wsum(float v) {
    #pragma unroll
    for (int o = 32; o > 0; o >>= 1) v += __shfl_xor(v, o);
    return v;
}
__device__ __forceinline__ float wmax(float v) {
    #pragma unroll
    for (int o = 32; o > 0; o >>= 1) v = fmaxf(v, __shfl_xor(v, o));
    return v;
}

// ---------------- weight preconvert: fp32 [Oreal][WLD] -> bf16 [Oalloc][KP], pad 0 ----
__global__ __launch_bounds__(256) void wconv_kernel(
    const float* __restrict__ src, bf16* __restrict__ dst,
    int Oreal, int Oalloc, int K, int KP, int WLD)
{
    const int idx = blockIdx.x * 256 + threadIdx.x;
    if (idx >= Oalloc * KP) return;
    const int o = idx / KP, k = idx % KP;
    float v = (o < Oreal && k < K) ? src[(size_t)o * WLD + k] : 0.f;
    dst[idx] = __float2bfloat16(v);
}

// ---------------- LayerNorm C=192: fp32 [b][192][N] -> bf16 [b][n][192] ----------------
__global__ __launch_bounds__(256) void ln_t_kernel(
    const float* __restrict__ X, const float* __restrict__ w,
    const float* __restrict__ bias, bf16* __restrict__ Y, int N)
{
    const int wv = threadIdx.x >> 6, ln_ = threadIdx.x & 63;
    const int p = blockIdx.x * 128 + wv * 32 + (ln_ & 31);   // flat pixel in B*N
    const int b = p >> 14, n = p & 16383;                    // N = 16384
    const int c0 = (ln_ >> 5) * 96;
    const float* xp = X + ((size_t)b * 192 + c0) * N + n;
    float s = 0.f, s2 = 0.f;
    #pragma unroll
    for (int c = 0; c < 96; c++) { float v = xp[(size_t)c * N]; s += v; s2 += v * v; }
    s += __shfl_xor(s, 32);
    s2 += __shfl_xor(s2, 32);
    const float mean = s * (1.f / 192.f);
    const float rstd = rsqrtf(s2 * (1.f / 192.f) - mean * mean + 1e-5f);
    bf16* yp = Y + ((size_t)(b * 16384 + n)) * 192 + c0;
    #pragma unroll
    for (int c = 0; c < 96; c += 2) {
        float v0 = (xp[(size_t)c * N] - mean) * rstd * w[c0 + c] + bias[c0 + c];
        float v1 = (xp[(size_t)(c + 1) * N] - mean) * rstd * w[c0 + c + 1] + bias[c0 + c + 1];
        unsigned u = (unsigned)(unsigned short)f2bf_bits(v0) |
                     ((unsigned)(unsigned short)f2bf_bits(v1) << 16);
        *(unsigned*)(yp + c) = u;
    }
}

// ---- weights-in-registers MFMA GEMM, XCD-swizzled: Y[b][o][n] = W[o][:].X[b][n][:] ----
template<int K, typename YT, bool RESID>
__global__ __launch_bounds__(256) void wreg_gemm_kernel(
    const bf16* __restrict__ Wb, const bf16* __restrict__ X,
    const float* __restrict__ Rsd, YT* __restrict__ Y,
    int O, int KS, int NROW, int NSTEP)
{
    constexpr int KST = K / 32;
    // bijective XCD swizzle: each XCD gets a contiguous work chunk, o fastest
    const int OT = gridDim.x, NT = gridDim.y;
    const int orig = blockIdx.x + OT * (blockIdx.y + NT * blockIdx.z);
    const int total = OT * NT * gridDim.z;
    const int qq = total >> 3, rr = total & 7;
    const int xcd = orig & 7, loc = orig >> 3;
    const int nw = (xcd < rr ? xcd * (qq + 1) : rr * (qq + 1) + (xcd - rr) * qq) + loc;
    const int o0 = (nw % OT) * 64;
    const int nbase = ((nw / OT) % NT) * NSTEP;
    const int b = nw / (OT * NT);

    const int wave = threadIdx.x >> 6, lane = threadIdx.x & 63;
    const int arow = lane & 15, kg = lane >> 4;

    short8 wf[KST];
    {
        const bf16* wp = Wb + (size_t)(o0 + wave * 16 + arow) * K + kg * 8;
        #pragma unroll
        for (int ks = 0; ks < KST; ks++) wf[ks] = *(const short8*)(wp + ks * 32);
    }
    const bf16* Xb = X + ((size_t)b * NROW + nbase) * KS;

    for (int nt = 0; nt < NSTEP; nt += 64) {
        f32x4 acc[4];
        #pragma unroll
        for (int s = 0; s < 4; s++) acc[s] = (f32x4){0.f, 0.f, 0.f, 0.f};
        #pragma unroll
        for (int s = 0; s < 4; s++) {
            const bf16* xp = Xb + (size_t)(nt + s * 16 + arow) * KS + kg * 8;
            #pragma unroll
            for (int ks = 0; ks < KST; ks++) {
                short8 bfr = *(const short8*)(xp + ks * 32);
                acc[s] = __builtin_amdgcn_mfma_f32_16x16x32_bf16(wf[ks], bfr, acc[s], 0, 0, 0);
            }
        }
        #pragma unroll
        for (int s = 0; s < 4; s++) {
            #pragma unroll
            for (int r = 0; r < 4; r++) {
                const int o = o0 + wave * 16 + kg * 4 + r;
                if (o < O) {
                    const size_t off = ((size_t)b * O + o) * NROW + nbase + nt + s * 16 + arow;
                    float v = acc[s][r];
                    if (RESID) v += Rsd[off];
                    storev(&Y[off], v);
                }
            }
        }
    }
}

// -------- tiled depthwise 3x3 (bf16 planes): block = 1 ch x 16 y x 128 x --------------
__global__ __launch_bounds__(256) void dwconv3_tile_kernel(
    const bf16* __restrict__ X, const float* __restrict__ Wd, bf16* __restrict__ Y,
    int CH)
{
    __shared__ short sm[18][144];   // x0 at col 8; zero halos at 7 and 136
    const int b = blockIdx.z, ch = blockIdx.y;
    const int y0 = blockIdx.x * 16;
    const int tid = threadIdx.x;
    const size_t base = ((size_t)b * CH + ch) * 16384;

    for (int idx = tid; idx < 288; idx += 256) {
        const int r = idx >> 4, xc = idx & 15;
        const int yy = y0 - 1 + r;
        short8 v = {0, 0, 0, 0, 0, 0, 0, 0};
        if (yy >= 0 && yy < 128) v = *(const short8*)(X + base + yy * 128 + xc * 8);
        *(short8*)&sm[r][8 + xc * 8] = v;
    }
    if (tid < 18) { sm[tid][7] = 0; sm[tid][136] = 0; }
    __syncthreads();

    float wv[9];
    #pragma unroll
    for (int i = 0; i < 9; i++) wv[i] = Wd[ch * 9 + i];

    const int ty = tid >> 4, x8 = (tid & 15) * 8;
    float a[8] = {0.f, 0.f, 0.f, 0.f, 0.f, 0.f, 0.f, 0.f};
    #pragma unroll
    for (int dy = 0; dy < 3; dy++) {
        const short* row = &sm[ty + dy][7 + x8];
        float p0 = s2f(row[0]);
        float p1 = s2f(row[1]);
        #pragma unroll
        for (int j = 0; j < 8; j++) {
            float p2 = s2f(row[j + 2]);
            a[j] += wv[dy * 3] * p0 + wv[dy * 3 + 1] * p1 + wv[dy * 3 + 2] * p2;
            p0 = p1; p1 = p2;
        }
    }
    short8 ov;
    #pragma unroll
    for (int j = 0; j < 8; j++) ((short*)&ov)[j] = f2bf_bits(a[j]);
    *(short8*)(Y + base + (size_t)(y0 + ty) * 128 + x8) = ov;
}

// ---- tiled fused dw3(f1)->gelu * dw3(f2) -> GT[b][n][512] ; block = 4 hc x 8 y x 128 x
__global__ __launch_bounds__(256) void dwgelu_tile_kernel(
    const bf16* __restrict__ F1, const bf16* __restrict__ F2,
    const float* __restrict__ Wd, bf16* __restrict__ GT)
{
    __shared__ short s1[4][10][144];
    __shared__ short s2[4][10][144];
    __shared__ short ot[4][1056];
    const int b = blockIdx.z;
    const int y0 = blockIdx.x * 8;
    const int hc0 = blockIdx.y * 4;
    const int tid = threadIdx.x;

    for (int idx = tid; idx < 640; idx += 256) {
        const int c = idx / 160, rem = idx % 160;
        const int r = rem >> 4, xc = rem & 15;
        const int yy = y0 - 1 + r;
        const int hc = hc0 + c;
        short8 v1 = {0,0,0,0,0,0,0,0}, v2 = v1;
        if (hc < 510 && yy >= 0 && yy < 128) {
            const size_t src = ((size_t)b * 510 + hc) * 16384 + (size_t)yy * 128 + xc * 8;
            v1 = *(const short8*)(F1 + src);
            v2 = *(const short8*)(F2 + src);
        }
        *(short8*)&s1[c][r][8 + xc * 8] = v1;
        *(short8*)&s2[c][r][8 + xc * 8] = v2;
    }
    if (tid < 40) {
        const int c = tid / 10, r = tid % 10;
        s1[c][r][7] = 0; s1[c][r][136] = 0;
        s2[c][r][7] = 0; s2[c][r][136] = 0;
    }
    __syncthreads();

    const int c = tid >> 6, xl = tid & 63;
    const int hc = hc0 + c;
    float w1[9], w2[9];
    #pragma unroll
    for (int i = 0; i < 9; i++) {
        w1[i] = (hc < 510) ? Wd[(size_t)hc * 9 + i] : 0.f;
        w2[i] = (hc < 510) ? Wd[(size_t)(510 + hc) * 9 + i] : 0.f;
    }
    const int xb = xl * 2;
    #pragma unroll
    for (int yy = 0; yy < 8; yy++) {
        float d1a = 0.f, d1b = 0.f, d2a = 0.f, d2b = 0.f;
        #pragma unroll
        for (int dy = 0; dy < 3; dy++) {
            const short* r1 = &s1[c][yy + dy][7 + xb];
            const short* r2 = &s2[c][yy + dy][7 + xb];
            float u0 = s2f(r1[0]), u1 = s2f(r1[1]), u2 = s2f(r1[2]), u3 = s2f(r1[3]);
            float t0 = s2f(r2[0]), t1 = s2f(r2[1]), t2 = s2f(r2[2]), t3 = s2f(r2[3]);
            d1a += w1[dy * 3] * u0 + w1[dy * 3 + 1] * u1 + w1[dy * 3 + 2] * u2;
            d1b += w1[dy * 3] * u1 + w1[dy * 3 + 1] * u2 + w1[dy * 3 + 2] * u3;
            d2a += w2[dy * 3] * t0 + w2[dy * 3 + 1] * t1 + w2[dy * 3 + 2] * t2;
            d2b += w2[dy * 3] * t1 + w2[dy * 3 + 1] * t2 + w2[dy * 3 + 2] * t3;
        }
        float ga = 0.5f * d1a * (1.f + erff(d1a * 0.70710678118654752f)) * d2a;
        float gb = 0.5f * d1b * (1.f + erff(d1b * 0.70710678118654752f)) * d2b;
        if (hc >= 510) { ga = 0.f; gb = 0.f; }
        ot[c][yy * 128 + xb] = f2bf_bits(ga);
        ot[c][yy * 128 + xb + 1] = f2bf_bits(gb);
    }
    __syncthreads();
    for (int idx = tid; idx < 1024; idx += 256) {
        short v0 = ot[0][idx], v1 = ot[1][idx], v2 = ot[2][idx], v3 = ot[3][idx];
        uint2 pk;
        pk.x = (unsigned)(unsigned short)v0 | ((unsigned)(unsigned short)v1 << 16);
        pk.y = (unsigned)(unsigned short)v2 | ((unsigned)(unsigned short)v3 << 16);
        *(uint2*)(GT + ((size_t)b * 16384 + y0 * 128 + idx) * 512 + hc0) = pk;
    }
}

// ---------------- row L2 norms (bf16 rows of length N) ----------------
__global__ __launch_bounds__(256) void rownorm_kernel(
    const bf16* __restrict__ X, float* __restrict__ inv, int N)
{
    const int row = blockIdx.x;
    const bf16* p = X + (size_t)row * N;
    float s = 0.f;
    for (int i = threadIdx.x; i < N; i += 256) { float v = tof(p[i]); s += v * v; }
    s = wsum(s);
    __shared__ float red[4];
    if ((threadIdx.x & 63) == 0) red[threadIdx.x >> 6] = s;
    __syncthreads();
    if (threadIdx.x == 0) {
        float t = red[0] + red[1] + red[2] + red[3];
        inv[row] = 1.f / fmaxf(sqrtf(t), 1e-12f);
    }
}

// ---------------- gram: attn_raw[bh,c,d] += sum_n q*k ; Q,K bf16 [B][192][N] ----------
__global__ __launch_bounds__(256) void gram_kernel(
    const bf16* __restrict__ Q, const bf16* __restrict__ K,
    float* __restrict__ attn_raw, int N)
{
    __shared__ float qs[48][65];
    __shared__ float ks[48][65];
    const int b = blockIdx.z, h = blockIdx.y;
    const int nbase = blockIdx.x * 1024;
    const bf16* Qb = Q + ((size_t)b * 192 + h * 48) * N;
    const bf16* Kb = K + ((size_t)b * 192 + h * 48) * N;
    const int tid = threadIdx.x;
    const int ci = (tid >> 4) * 3, di = (tid & 15) * 3;
    float acc[3][3] = {};
    for (int t = 0; t < 16; t++) {
        const int n0 = nbase + t * 64;
        for (int i = 0; i < 12; i++) {
            const int idx = tid + i * 256;
            const int r = idx >> 6, cn = idx & 63;
            qs[r][cn] = tof(Qb[(size_t)r * N + n0 + cn]);
            ks[r][cn] = tof(Kb[(size_t)r * N + n0 + cn]);
        }
        __syncthreads();
        for (int n = 0; n < 64; n++) {
            float qv[3], kv[3];
            #pragma unroll
            for (int i = 0; i < 3; i++) qv[i] = qs[ci + i][n];
            #pragma unroll
            for (int j = 0; j < 3; j++) kv[j] = ks[di + j][n];
            #pragma unroll
            for (int i = 0; i < 3; i++)
                #pragma unroll
                for (int j = 0; j < 3; j++) acc[i][j] += qv[i] * kv[j];
        }
        __syncthreads();
    }
    float* A = attn_raw + ((size_t)(b * 4 + h)) * 2304;
    #pragma unroll
    for (int i = 0; i < 3; i++)
        #pragma unroll
        for (int j = 0; j < 3; j++) atomicAdd(&A[(ci + i) * 48 + di + j], acc[i][j]);
}

// ---------------- top-k(4 ways) sparsified softmax combine ----------------
__global__ __launch_bounds__(64) void topk_kernel(
    const float* __restrict__ attn_raw, const float* __restrict__ invq,
    const float* __restrict__ invk, const float* __restrict__ temp,
    const float* __restrict__ mix, float* __restrict__ Acomb)
{
    const int rowid = blockIdx.x;  // bh*48 + c
    const int c = rowid % 48, bh = rowid / 48, h = bh & 3, b = bh >> 2;
    const int lane = threadIdx.x;
    __shared__ float a[48];
    const float iq = invq[b * 192 + h * 48 + c] * temp[h];
    if (lane < 48)
        a[lane] = attn_raw[(size_t)bh * 2304 + c * 48 + lane] * iq * invk[b * 192 + h * 48 + lane];
    __syncthreads();
    const float av = (lane < 48) ? a[lane] : -INFINITY;
    int cnt_gt = 0, cnt_ge = 0;
    if (lane < 48) {
        for (int j = 0; j < 48; j++) { cnt_gt += (a[j] > av); cnt_ge += (a[j] >= av); }
    }
    const float m = wmax(av);
    const float p = (lane < 48) ? expf(av - m) : 0.f;
    float coeff = 0.f;
    const int kks[4] = {24, 32, 36, 38};
    #pragma unroll
    for (int i = 0; i < 4; i++) {
        const int kk = kks[i];
        float cand = (lane < 48 && cnt_gt < kk && cnt_ge >= kk) ? av : -INFINITY;
        cand = wmax(cand);
        const bool pass = (lane < 48) && (av >= cand);
        float z = wsum(pass ? p : 0.f);
        coeff += pass ? (mix[i] / z) : 0.f;
    }
    if (lane < 48) Acomb[(size_t)bh * 2304 + c * 48 + lane] = p * coeff;
}

// ---------------- attn_out (T-layout bf16 [b][n][192]) = Acomb @ v ----------------
__global__ __launch_bounds__(256) void attnv_kernel(
    const float* __restrict__ Acomb, const bf16* __restrict__ V,
    bf16* __restrict__ OT, int N)
{
    __shared__ float As[48][48];
    __shared__ float vs[48][64];
    __shared__ bf16 ot[64][48];
    const int b = blockIdx.z, h = blockIdx.y;
    const int n0 = blockIdx.x * 64;
    const float* Ap = Acomb + (size_t)(b * 4 + h) * 2304;
    for (int i = threadIdx.x; i < 2304; i += 256) As[i / 48][i % 48] = Ap[i];
    const bf16* Vb = V + ((size_t)b * 192 + h * 48) * N;
    for (int i = threadIdx.x; i < 3072; i += 256) {
        const int r = i >> 6, cn = i & 63;
        vs[r][cn] = tof(Vb[(size_t)r * N + n0 + cn]);
    }
    __syncthreads();
    const int nl = threadIdx.x & 63;
    const int cg = threadIdx.x >> 6;
    for (int c = cg * 12; c < cg * 12 + 12; c++) {
        float s = 0.f;
        #pragma unroll
        for (int d = 0; d < 48; d++) s += As[c][d] * vs[d][nl];
        ot[nl][c] = __float2bfloat16(s);
    }
    __syncthreads();
    for (int idx = threadIdx.x; idx < 384; idx += 256) {
        const int r = idx / 6, q = idx % 6;
        *(uint4*)((char*)&OT[((size_t)b * N + n0 + r) * 192 + h * 48] + q * 16) =
            *(uint4*)((char*)&ot[r][0] + q * 16);
    }
}

// ---------------- launch ----------------
extern "C" void kernel_launch(void* const* d_in, const int* in_sizes, int n_in,
                              void* d_out, int out_size, void* d_ws, size_t ws_size,
                              hipStream_t stream)
{
    const float* x       = (const float*)d_in[0];
    const float* y       = (const float*)d_in[1];
    const float* ln1_w   = (const float*)d_in[2];
    const float* ln1_b   = (const float*)d_in[3];
    const float* ln2_w   = (const float*)d_in[4];
    const float* ln2_b   = (const float*)d_in[5];
    const float* kv_w    = (const float*)d_in[6];
    const float* kv_dw   = (const float*)d_in[7];
    const float* q_w     = (const float*)d_in[8];
    const float* q_dw    = (const float*)d_in[9];
    const float* po_w    = (const float*)d_in[10];
    const float* temp    = (const float*)d_in[11];
    const float* mix     = (const float*)d_in[12];
    const float* ffn_in_w  = (const float*)d_in[13];
    const float* ffn_dw    = (const float*)d_in[14];
    const float* ffn_out_w = (const float*)d_in[15];
    float* out = (float*)d_out;

    const int N = 16384;
    const size_t TB = (size_t)4 * N * 192 * 2;   // 25,165,824 bytes

    char* ws = (char*)d_ws;
    bf16* XT0 = (bf16*)ws;                        // yn / xn / xn2 (T-layout)
    bf16* XT1 = (bf16*)(ws + TB);                 // q/k/v_pre then attn_outT
    bf16* Q   = (bf16*)(ws + 2 * TB);
    bf16* Kb  = (bf16*)(ws + 3 * TB);
    bf16* V   = (bf16*)(ws + 4 * TB);
    float* S  = (float*)(ws + 5 * TB);            // @ 125,829,120
    float* invq = S;
    float* invk = S + 768;
    float* attn_raw = S + 1536;
    float* Acomb = attn_raw + 16 * 48 * 48;       // S region < 310 KB
    // bf16 weights after S region
    bf16* Wq  = (bf16*)(ws + 5 * TB + 331776);
    bf16* Wkv = Wq + 36864;        // 384x192
    bf16* Wpo = Wkv + 73728;       // 192x192
    bf16* Wfi = Wpo + 36864;       // 1024x192 (1020 real + 4 zero rows)
    bf16* Wfo = Wfi + 196608;      // 192x512  (K padded 510->512)
    // FFN overlay (attention buffers dead): F1/F2/GT over XT1..V
    bf16* F1 = (bf16*)(ws + TB);                          // [2][510][N]
    bf16* F2 = (bf16*)(ws + TB + (size_t)33423360);
    bf16* GT = (bf16*)(ws + TB + 2 * (size_t)33423360);   // [2][N][512]

    const dim3 blk(256);
    const dim3 ln_grid(4 * N / 128);
    const dim3 dwg(8, 192, 4);

    // ---- preconvert weights to bf16 ----
    wconv_kernel<<<dim3((192 * 192 + 255) / 256), blk, 0, stream>>>(q_w, Wq, 192, 192, 192, 192, 192);
    wconv_kernel<<<dim3((384 * 192 + 255) / 256), blk, 0, stream>>>(kv_w, Wkv, 384, 384, 192, 192, 192);
    wconv_kernel<<<dim3((192 * 192 + 255) / 256), blk, 0, stream>>>(po_w, Wpo, 192, 192, 192, 192, 192);
    wconv_kernel<<<dim3((1024 * 192 + 255) / 256), blk, 0, stream>>>(ffn_in_w, Wfi, 1020, 1024, 192, 192, 192);
    wconv_kernel<<<dim3((192 * 512 + 255) / 256), blk, 0, stream>>>(ffn_out_w, Wfo, 192, 192, 510, 512, 510);

    // ---- q path ----
    ln_t_kernel<<<ln_grid, blk, 0, stream>>>(y, ln1_w, ln1_b, XT0, N);
    wreg_gemm_kernel<192, bf16, false><<<dim3(3, N / 128, 4), blk, 0, stream>>>(Wq, XT0, nullptr, XT1, 192, 192, N, 128);
    dwconv3_tile_kernel<<<dwg, blk, 0, stream>>>(XT1, q_dw, Q, 192);
    // ---- k, v path ----
    ln_t_kernel<<<ln_grid, blk, 0, stream>>>(x, ln1_w, ln1_b, XT0, N);
    wreg_gemm_kernel<192, bf16, false><<<dim3(3, N / 128, 4), blk, 0, stream>>>(Wkv, XT0, nullptr, XT1, 192, 192, N, 128);
    dwconv3_tile_kernel<<<dwg, blk, 0, stream>>>(XT1, kv_dw, Kb, 192);
    wreg_gemm_kernel<192, bf16, false><<<dim3(3, N / 128, 4), blk, 0, stream>>>(Wkv + 192 * 192, XT0, nullptr, XT1, 192, 192, N, 128);
    dwconv3_tile_kernel<<<dwg, blk, 0, stream>>>(XT1, kv_dw + 192 * 9, V, 192);
    // ---- norms, attention matrix, combine ----
    rownorm_kernel<<<dim3(768), blk, 0, stream>>>(Q, invq, N);
    rownorm_kernel<<<dim3(768), blk, 0, stream>>>(Kb, invk, N);
    hipMemsetAsync(attn_raw, 0, 16 * 48 * 48 * 4, stream);
    gram_kernel<<<dim3(16, 4, 4), blk, 0, stream>>>(Q, Kb, attn_raw, N);
    topk_kernel<<<dim3(768), dim3(64), 0, stream>>>(attn_raw, invq, invk, temp, mix, Acomb);
    // ---- attn_out (T) -> XT1 ; x1 = x + po(attn_out) -> out ----
    attnv_kernel<<<dim3(N / 64, 4, 4), blk, 0, stream>>>(Acomb, V, XT1, N);
    wreg_gemm_kernel<192, float, true><<<dim3(3, N / 128, 4), blk, 0, stream>>>(Wpo, XT1, x, out, 192, 192, N, 128);
    // ---- FFN ----
    ln_t_kernel<<<ln_grid, blk, 0, stream>>>(out, ln2_w, ln2_b, XT0, N);
    for (int bp = 0; bp < 2; bp++) {
        const bf16* X2 = XT0 + (size_t)bp * 2 * N * 192;
        float* Ybp = out + (size_t)bp * 2 * 192 * N;
        wreg_gemm_kernel<192, bf16, false><<<dim3(8, N / 256, 2), blk, 0, stream>>>(Wfi, X2, nullptr, F1, 510, 192, N, 256);
        wreg_gemm_kernel<192, bf16, false><<<dim3(8, N / 256, 2), blk, 0, stream>>>(Wfi + (size_t)510 * 192, X2, nullptr, F2, 510, 192, N, 256);
        dwgelu_tile_kernel<<<dim3(16, 128, 2), blk, 0, stream>>>(F1, F2, ffn_dw, GT);
        wreg_gemm_kernel<512, float, true><<<dim3(3, N / 128, 2), blk, 0, stream>>>(Wfo, GT, Ybp, Ybp, 192, 512, N, 128);
    }
}

// Round 8
// 917.215 us; speedup vs baseline: 2.2973x; 1.0953x over previous
//
#include <hip/hip_runtime.h>
#include <hip/hip_bf16.h>

using bf16 = __hip_bfloat16;
typedef __attribute__((ext_vector_type(8))) short short8;
typedef __attribute__((ext_vector_type(4))) float f32x4;

// ---------------- helpers ----------------
__device__ __forceinline__ float tof(float v) { return v; }
__device__ __forceinline__ float tof(bf16 v) { return __bfloat162float(v); }
__device__ __forceinline__ float s2f(short s) {
    return __uint_as_float(((unsigned)(unsigned short)s) << 16);
}
__device__ __forceinline__ void storev(float* p, float v) { *p = v; }
__device__ __forceinline__ void storev(bf16* p, float v) { *p = __float2bfloat16(v); }
__device__ __forceinline__ short f2bf_bits(float v) {
    bf16 h = __float2bfloat16(v);
    return *(short*)&h;
}
__device__ __forceinline__ float wsum(float v) {
    #pragma unroll
    for (int o = 32; o > 0; o >>= 1) v += __shfl_xor(v, o);
    return v;
}
__device__ __forceinline__ float wmax(float v) {
    #pragma unroll
    for (int o = 32; o > 0; o >>= 1) v = fmaxf(v, __shfl_xor(v, o));
    return v;
}

// ---------------- weight preconvert: fp32 [Oreal][WLD] -> bf16 [Oalloc][KP], pad 0 ----
__global__ __launch_bounds__(256) void wconv_kernel(
    const float* __restrict__ src, bf16* __restrict__ dst,
    int Oreal, int Oalloc, int K, int KP, int WLD)
{
    const int idx = blockIdx.x * 256 + threadIdx.x;
    if (idx >= Oalloc * KP) return;
    const int o = idx / KP, k = idx % KP;
    float v = (o < Oreal && k < K) ? src[(size_t)o * WLD + k] : 0.f;
    dst[idx] = __float2bfloat16(v);
}

// ---------------- LayerNorm C=192: fp32 [b][192][N] -> bf16 [b][n][192] ----------------
__global__ __launch_bounds__(256) void ln_t_kernel(
    const float* __restrict__ X, const float* __restrict__ w,
    const float* __restrict__ bias, bf16* __restrict__ Y, int N)
{
    const int wv = threadIdx.x >> 6, ln_ = threadIdx.x & 63;
    const int p = blockIdx.x * 128 + wv * 32 + (ln_ & 31);   // flat pixel in B*N
    const int b = p >> 14, n = p & 16383;                    // N = 16384
    const int c0 = (ln_ >> 5) * 96;
    const float* xp = X + ((size_t)b * 192 + c0) * N + n;
    float s = 0.f, s2 = 0.f;
    #pragma unroll
    for (int c = 0; c < 96; c++) { float v = xp[(size_t)c * N]; s += v; s2 += v * v; }
    s += __shfl_xor(s, 32);
    s2 += __shfl_xor(s2, 32);
    const float mean = s * (1.f / 192.f);
    const float rstd = rsqrtf(s2 * (1.f / 192.f) - mean * mean + 1e-5f);
    bf16* yp = Y + ((size_t)(b * 16384 + n)) * 192 + c0;
    #pragma unroll
    for (int c = 0; c < 96; c += 2) {
        float v0 = (xp[(size_t)c * N] - mean) * rstd * w[c0 + c] + bias[c0 + c];
        float v1 = (xp[(size_t)(c + 1) * N] - mean) * rstd * w[c0 + c + 1] + bias[c0 + c + 1];
        unsigned u = (unsigned)(unsigned short)f2bf_bits(v0) |
                     ((unsigned)(unsigned short)f2bf_bits(v1) << 16);
        *(unsigned*)(yp + c) = u;
    }
}

// ---- weights-in-registers MFMA GEMM, XCD-swizzled: Y[b][o][n] = W[o][:].X[b][n][:] ----
template<int K, typename YT, bool RESID>
__global__ __launch_bounds__(256) void wreg_gemm_kernel(
    const bf16* __restrict__ Wb, const bf16* __restrict__ X,
    const float* __restrict__ Rsd, YT* __restrict__ Y,
    int O, int KS, int NROW, int NSTEP)
{
    constexpr int KST = K / 32;
    // bijective XCD swizzle: each XCD gets a contiguous work chunk, o fastest
    const int OT = gridDim.x, NT = gridDim.y;
    const int orig = blockIdx.x + OT * (blockIdx.y + NT * blockIdx.z);
    const int total = OT * NT * gridDim.z;
    const int qq = total >> 3, rr = total & 7;
    const int xcd = orig & 7, loc = orig >> 3;
    const int nw = (xcd < rr ? xcd * (qq + 1) : rr * (qq + 1) + (xcd - rr) * qq) + loc;
    const int o0 = (nw % OT) * 64;
    const int nbase = ((nw / OT) % NT) * NSTEP;
    const int b = nw / (OT * NT);

    const int wave = threadIdx.x >> 6, lane = threadIdx.x & 63;
    const int arow = lane & 15, kg = lane >> 4;

    short8 wf[KST];
    {
        const bf16* wp = Wb + (size_t)(o0 + wave * 16 + arow) * K + kg * 8;
        #pragma unroll
        for (int ks = 0; ks < KST; ks++) wf[ks] = *(const short8*)(wp + ks * 32);
    }
    const bf16* Xb = X + ((size_t)b * NROW + nbase) * KS;

    for (int nt = 0; nt < NSTEP; nt += 64) {
        f32x4 acc[4];
        #pragma unroll
        for (int s = 0; s < 4; s++) acc[s] = (f32x4){0.f, 0.f, 0.f, 0.f};
        #pragma unroll
        for (int s = 0; s < 4; s++) {
            const bf16* xp = Xb + (size_t)(nt + s * 16 + arow) * KS + kg * 8;
            #pragma unroll
            for (int ks = 0; ks < KST; ks++) {
                short8 bfr = *(const short8*)(xp + ks * 32);
                acc[s] = __builtin_amdgcn_mfma_f32_16x16x32_bf16(wf[ks], bfr, acc[s], 0, 0, 0);
            }
        }
        #pragma unroll
        for (int s = 0; s < 4; s++) {
            #pragma unroll
            for (int r = 0; r < 4; r++) {
                const int o = o0 + wave * 16 + kg * 4 + r;
                if (o < O) {
                    const size_t off = ((size_t)b * O + o) * NROW + nbase + nt + s * 16 + arow;
                    float v = acc[s][r];
                    if (RESID) v += Rsd[off];
                    storev(&Y[off], v);
                }
            }
        }
    }
}

// -------- tiled depthwise 3x3 (bf16 planes): block = 1 ch x 16 y x 128 x --------------
__global__ __launch_bounds__(256) void dwconv3_tile_kernel(
    const bf16* __restrict__ X, const float* __restrict__ Wd, bf16* __restrict__ Y,
    int CH)
{
    __shared__ short sm[18][144];   // x0 at col 8; zero halos at 7 and 136
    const int b = blockIdx.z, ch = blockIdx.y;
    const int y0 = blockIdx.x * 16;
    const int tid = threadIdx.x;
    const size_t base = ((size_t)b * CH + ch) * 16384;

    for (int idx = tid; idx < 288; idx += 256) {
        const int r = idx >> 4, xc = idx & 15;
        const int yy = y0 - 1 + r;
        short8 v = {0, 0, 0, 0, 0, 0, 0, 0};
        if (yy >= 0 && yy < 128) v = *(const short8*)(X + base + yy * 128 + xc * 8);
        *(short8*)&sm[r][8 + xc * 8] = v;
    }
    if (tid < 18) { sm[tid][7] = 0; sm[tid][136] = 0; }
    __syncthreads();

    float wv[9];
    #pragma unroll
    for (int i = 0; i < 9; i++) wv[i] = Wd[ch * 9 + i];

    const int ty = tid >> 4, x8 = (tid & 15) * 8;
    float a[8] = {0.f, 0.f, 0.f, 0.f, 0.f, 0.f, 0.f, 0.f};
    #pragma unroll
    for (int dy = 0; dy < 3; dy++) {
        const short* row = &sm[ty + dy][7 + x8];
        float p0 = s2f(row[0]);
        float p1 = s2f(row[1]);
        #pragma unroll
        for (int j = 0; j < 8; j++) {
            float p2 = s2f(row[j + 2]);
            a[j] += wv[dy * 3] * p0 + wv[dy * 3 + 1] * p1 + wv[dy * 3 + 2] * p2;
            p0 = p1; p1 = p2;
        }
    }
    short8 ov;
    #pragma unroll
    for (int j = 0; j < 8; j++) ((short*)&ov)[j] = f2bf_bits(a[j]);
    *(short8*)(Y + base + (size_t)(y0 + ty) * 128 + x8) = ov;
}

// ---- tiled fused dw3(f1)->gelu * dw3(f2) -> GT[b][n][512] ; block = 4 hc x 8 y x 128 x
__global__ __launch_bounds__(256) void dwgelu_tile_kernel(
    const bf16* __restrict__ F1, const bf16* __restrict__ F2,
    const float* __restrict__ Wd, bf16* __restrict__ GT)
{
    __shared__ short s1[4][10][144];
    __shared__ short s2[4][10][144];
    __shared__ short ot[4][1056];
    const int b = blockIdx.z;
    const int y0 = blockIdx.x * 8;
    const int hc0 = blockIdx.y * 4;
    const int tid = threadIdx.x;

    for (int idx = tid; idx < 640; idx += 256) {
        const int c = idx / 160, rem = idx % 160;
        const int r = rem >> 4, xc = rem & 15;
        const int yy = y0 - 1 + r;
        const int hc = hc0 + c;
        short8 v1 = {0,0,0,0,0,0,0,0}, v2 = v1;
        if (hc < 510 && yy >= 0 && yy < 128) {
            const size_t src = ((size_t)b * 510 + hc) * 16384 + (size_t)yy * 128 + xc * 8;
            v1 = *(const short8*)(F1 + src);
            v2 = *(const short8*)(F2 + src);
        }
        *(short8*)&s1[c][r][8 + xc * 8] = v1;
        *(short8*)&s2[c][r][8 + xc * 8] = v2;
    }
    if (tid < 40) {
        const int c = tid / 10, r = tid % 10;
        s1[c][r][7] = 0; s1[c][r][136] = 0;
        s2[c][r][7] = 0; s2[c][r][136] = 0;
    }
    __syncthreads();

    const int c = tid >> 6, xl = tid & 63;
    const int hc = hc0 + c;
    float w1[9], w2[9];
    #pragma unroll
    for (int i = 0; i < 9; i++) {
        w1[i] = (hc < 510) ? Wd[(size_t)hc * 9 + i] : 0.f;
        w2[i] = (hc < 510) ? Wd[(size_t)(510 + hc) * 9 + i] : 0.f;
    }
    const int xb = xl * 2;
    #pragma unroll
    for (int yy = 0; yy < 8; yy++) {
        float d1a = 0.f, d1b = 0.f, d2a = 0.f, d2b = 0.f;
        #pragma unroll
        for (int dy = 0; dy < 3; dy++) {
            const short* r1 = &s1[c][yy + dy][7 + xb];
            const short* r2 = &s2[c][yy + dy][7 + xb];
            float u0 = s2f(r1[0]), u1 = s2f(r1[1]), u2 = s2f(r1[2]), u3 = s2f(r1[3]);
            float t0 = s2f(r2[0]), t1 = s2f(r2[1]), t2 = s2f(r2[2]), t3 = s2f(r2[3]);
            d1a += w1[dy * 3] * u0 + w1[dy * 3 + 1] * u1 + w1[dy * 3 + 2] * u2;
            d1b += w1[dy * 3] * u1 + w1[dy * 3 + 1] * u2 + w1[dy * 3 + 2] * u3;
            d2a += w2[dy * 3] * t0 + w2[dy * 3 + 1] * t1 + w2[dy * 3 + 2] * t2;
            d2b += w2[dy * 3] * t1 + w2[dy * 3 + 1] * t2 + w2[dy * 3 + 2] * t3;
        }
        float ga = 0.5f * d1a * (1.f + erff(d1a * 0.70710678118654752f)) * d2a;
        float gb = 0.5f * d1b * (1.f + erff(d1b * 0.70710678118654752f)) * d2b;
        if (hc >= 510) { ga = 0.f; gb = 0.f; }
        ot[c][yy * 128 + xb] = f2bf_bits(ga);
        ot[c][yy * 128 + xb + 1] = f2bf_bits(gb);
    }
    __syncthreads();
    for (int idx = tid; idx < 1024; idx += 256) {
        short v0 = ot[0][idx], v1 = ot[1][idx], v2 = ot[2][idx], v3 = ot[3][idx];
        uint2 pk;
        pk.x = (unsigned)(unsigned short)v0 | ((unsigned)(unsigned short)v1 << 16);
        pk.y = (unsigned)(unsigned short)v2 | ((unsigned)(unsigned short)v3 << 16);
        *(uint2*)(GT + ((size_t)b * 16384 + y0 * 128 + idx) * 512 + hc0) = pk;
    }
}

// ---------------- row L2 norms (bf16 rows of length N), short8 loads ----------------
__global__ __launch_bounds__(256) void rownorm_kernel(
    const bf16* __restrict__ X, float* __restrict__ inv, int N)
{
    const int row = blockIdx.x;
    const bf16* p = X + (size_t)row * N;
    float s = 0.f;
    for (int i = threadIdx.x * 8; i < N; i += 2048) {
        short8 v = *(const short8*)(p + i);
        #pragma unroll
        for (int j = 0; j < 8; j++) { float f = s2f(((short*)&v)[j]); s += f * f; }
    }
    s = wsum(s);
    __shared__ float red[4];
    if ((threadIdx.x & 63) == 0) red[threadIdx.x >> 6] = s;
    __syncthreads();
    if (threadIdx.x == 0) {
        float t = red[0] + red[1] + red[2] + red[3];
        inv[row] = 1.f / fmaxf(sqrtf(t), 1e-12f);
    }
}

// ------- gram via MFMA: attn_raw[bh][c][d] += sum_n q[c,n]*k[d,n] over n-chunk --------
// block = 3 waves; wave = one 16-row c-strip; 3 f32x4 accs cover the 3 d-strips.
__global__ __launch_bounds__(192) void gram_mfma_kernel(
    const bf16* __restrict__ Q, const bf16* __restrict__ K,
    float* __restrict__ attn_raw, int N)
{
    const int b = blockIdx.z, h = blockIdx.y;
    const int n0base = blockIdx.x * 512;
    const int wave = threadIdx.x >> 6, lane = threadIdx.x & 63;
    const int arow = lane & 15, kg = lane >> 4;
    const bf16* Qb = Q + ((size_t)b * 192 + h * 48 + wave * 16 + arow) * N;
    const bf16* Kb = K + ((size_t)b * 192 + h * 48) * N;

    f32x4 acc[3];
    #pragma unroll
    for (int di = 0; di < 3; di++) acc[di] = (f32x4){0.f, 0.f, 0.f, 0.f};

    #pragma unroll 4
    for (int t = 0; t < 16; t++) {
        const int n0 = n0base + t * 32 + kg * 8;
        short8 a = *(const short8*)(Qb + n0);
        #pragma unroll
        for (int di = 0; di < 3; di++) {
            short8 bfr = *(const short8*)(Kb + (size_t)(di * 16 + arow) * N + n0);
            acc[di] = __builtin_amdgcn_mfma_f32_16x16x32_bf16(a, bfr, acc[di], 0, 0, 0);
        }
    }
    float* A = attn_raw + (size_t)(b * 4 + h) * 2304;
    const int c = wave * 16 + kg * 4;
    #pragma unroll
    for (int di = 0; di < 3; di++)
        #pragma unroll
        for (int r = 0; r < 4; r++)
            atomicAdd(&A[(c + r) * 48 + di * 16 + arow], acc[di][r]);
}

// ---------------- top-k(4 ways) sparsified softmax combine ----------------
__global__ __launch_bounds__(64) void topk_kernel(
    const float* __restrict__ attn_raw, const float* __restrict__ invq,
    const float* __restrict__ invk, const float* __restrict__ temp,
    const float* __restrict__ mix, float* __restrict__ Acomb)
{
    const int rowid = blockIdx.x;  // bh*48 + c
    const int c = rowid % 48, bh = rowid / 48, h = bh & 3, b = bh >> 2;
    const int lane = threadIdx.x;
    __shared__ float a[48];
    const float iq = invq[b * 192 + h * 48 + c] * temp[h];
    if (lane < 48)
        a[lane] = attn_raw[(size_t)bh * 2304 + c * 48 + lane] * iq * invk[b * 192 + h * 48 + lane];
    __syncthreads();
    const float av = (lane < 48) ? a[lane] : -INFINITY;
    int cnt_gt = 0, cnt_ge = 0;
    if (lane < 48) {
        for (int j = 0; j < 48; j++) { cnt_gt += (a[j] > av); cnt_ge += (a[j] >= av); }
    }
    const float m = wmax(av);
    const float p = (lane < 48) ? expf(av - m) : 0.f;
    float coeff = 0.f;
    const int kks[4] = {24, 32, 36, 38};
    #pragma unroll
    for (int i = 0; i < 4; i++) {
        const int kk = kks[i];
        float cand = (lane < 48 && cnt_gt < kk && cnt_ge >= kk) ? av : -INFINITY;
        cand = wmax(cand);
        const bool pass = (lane < 48) && (av >= cand);
        float z = wsum(pass ? p : 0.f);
        coeff += pass ? (mix[i] / z) : 0.f;
    }
    if (lane < 48) Acomb[(size_t)bh * 2304 + c * 48 + lane] = p * coeff;
}

// ---------------- attn_out (T-layout bf16 [b][n][192]) = Acomb @ v ----------------
__global__ __launch_bounds__(256) void attnv_kernel(
    const float* __restrict__ Acomb, const bf16* __restrict__ V,
    bf16* __restrict__ OT, int N)
{
    __shared__ float As[48][48];
    __shared__ float vs[48][64];
    __shared__ bf16 ot[64][48];
    const int b = blockIdx.z, h = blockIdx.y;
    const int n0 = blockIdx.x * 64;
    const float* Ap = Acomb + (size_t)(b * 4 + h) * 2304;
    for (int i = threadIdx.x; i < 2304; i += 256) As[i / 48][i % 48] = Ap[i];
    const bf16* Vb = V + ((size_t)b * 192 + h * 48) * N;
    for (int i = threadIdx.x; i < 3072; i += 256) {
        const int r = i >> 6, cn = i & 63;
        vs[r][cn] = tof(Vb[(size_t)r * N + n0 + cn]);
    }
    __syncthreads();
    const int nl = threadIdx.x & 63;
    const int cg = threadIdx.x >> 6;
    for (int c = cg * 12; c < cg * 12 + 12; c++) {
        float s = 0.f;
        #pragma unroll
        for (int d = 0; d < 48; d++) s += As[c][d] * vs[d][nl];
        ot[nl][c] = __float2bfloat16(s);
    }
    __syncthreads();
    for (int idx = threadIdx.x; idx < 384; idx += 256) {
        const int r = idx / 6, q = idx % 6;
        *(uint4*)((char*)&OT[((size_t)b * N + n0 + r) * 192 + h * 48] + q * 16) =
            *(uint4*)((char*)&ot[r][0] + q * 16);
    }
}

// ---------------- launch ----------------
extern "C" void kernel_launch(void* const* d_in, const int* in_sizes, int n_in,
                              void* d_out, int out_size, void* d_ws, size_t ws_size,
                              hipStream_t stream)
{
    const float* x       = (const float*)d_in[0];
    const float* y       = (const float*)d_in[1];
    const float* ln1_w   = (const float*)d_in[2];
    const float* ln1_b   = (const float*)d_in[3];
    const float* ln2_w   = (const float*)d_in[4];
    const float* ln2_b   = (const float*)d_in[5];
    const float* kv_w    = (const float*)d_in[6];
    const float* kv_dw   = (const float*)d_in[7];
    const float* q_w     = (const float*)d_in[8];
    const float* q_dw    = (const float*)d_in[9];
    const float* po_w    = (const float*)d_in[10];
    const float* temp    = (const float*)d_in[11];
    const float* mix     = (const float*)d_in[12];
    const float* ffn_in_w  = (const float*)d_in[13];
    const float* ffn_dw    = (const float*)d_in[14];
    const float* ffn_out_w = (const float*)d_in[15];
    float* out = (float*)d_out;

    const int N = 16384;
    const size_t TB = (size_t)4 * N * 192 * 2;   // 25,165,824 bytes

    char* ws = (char*)d_ws;
    bf16* XT0 = (bf16*)ws;                        // yn / xn / xn2 (T-layout)
    bf16* XT1 = (bf16*)(ws + TB);                 // q/k/v_pre then attn_outT
    bf16* Q   = (bf16*)(ws + 2 * TB);
    bf16* Kb  = (bf16*)(ws + 3 * TB);
    bf16* V   = (bf16*)(ws + 4 * TB);
    float* S  = (float*)(ws + 5 * TB);            // @ 125,829,120
    float* invq = S;
    float* invk = S + 768;
    float* attn_raw = S + 1536;
    float* Acomb = attn_raw + 16 * 48 * 48;       // S region < 310 KB
    // bf16 weights after S region
    bf16* Wq  = (bf16*)(ws + 5 * TB + 331776);
    bf16* Wkv = Wq + 36864;        // 384x192
    bf16* Wpo = Wkv + 73728;       // 192x192
    bf16* Wfi = Wpo + 36864;       // 1024x192 (1020 real + 4 zero rows)
    bf16* Wfo = Wfi + 196608;      // 192x512  (K padded 510->512)
    // FFN overlay (attention buffers dead): F1/F2/GT over XT1..V
    bf16* F1 = (bf16*)(ws + TB);                          // [2][510][N]
    bf16* F2 = (bf16*)(ws + TB + (size_t)33423360);
    bf16* GT = (bf16*)(ws + TB + 2 * (size_t)33423360);   // [2][N][512]

    const dim3 blk(256);
    const dim3 ln_grid(4 * N / 128);
    const dim3 dwg(8, 192, 4);

    // ---- preconvert weights to bf16 ----
    wconv_kernel<<<dim3((192 * 192 + 255) / 256), blk, 0, stream>>>(q_w, Wq, 192, 192, 192, 192, 192);
    wconv_kernel<<<dim3((384 * 192 + 255) / 256), blk, 0, stream>>>(kv_w, Wkv, 384, 384, 192, 192, 192);
    wconv_kernel<<<dim3((192 * 192 + 255) / 256), blk, 0, stream>>>(po_w, Wpo, 192, 192, 192, 192, 192);
    wconv_kernel<<<dim3((1024 * 192 + 255) / 256), blk, 0, stream>>>(ffn_in_w, Wfi, 1020, 1024, 192, 192, 192);
    wconv_kernel<<<dim3((192 * 512 + 255) / 256), blk, 0, stream>>>(ffn_out_w, Wfo, 192, 192, 510, 512, 510);

    // ---- q path ----
    ln_t_kernel<<<ln_grid, blk, 0, stream>>>(y, ln1_w, ln1_b, XT0, N);
    wreg_gemm_kernel<192, bf16, false><<<dim3(3, N / 128, 4), blk, 0, stream>>>(Wq, XT0, nullptr, XT1, 192, 192, N, 128);
    dwconv3_tile_kernel<<<dwg, blk, 0, stream>>>(XT1, q_dw, Q, 192);
    // ---- k, v path ----
    ln_t_kernel<<<ln_grid, blk, 0, stream>>>(x, ln1_w, ln1_b, XT0, N);
    wreg_gemm_kernel<192, bf16, false><<<dim3(3, N / 128, 4), blk, 0, stream>>>(Wkv, XT0, nullptr, XT1, 192, 192, N, 128);
    dwconv3_tile_kernel<<<dwg, blk, 0, stream>>>(XT1, kv_dw, Kb, 192);
    wreg_gemm_kernel<192, bf16, false><<<dim3(3, N / 128, 4), blk, 0, stream>>>(Wkv + 192 * 192, XT0, nullptr, XT1, 192, 192, N, 128);
    dwconv3_tile_kernel<<<dwg, blk, 0, stream>>>(XT1, kv_dw + 192 * 9, V, 192);
    // ---- norms, attention matrix, combine ----
    rownorm_kernel<<<dim3(768), blk, 0, stream>>>(Q, invq, N);
    rownorm_kernel<<<dim3(768), blk, 0, stream>>>(Kb, invk, N);
    hipMemsetAsync(attn_raw, 0, 16 * 48 * 48 * 4, stream);
    gram_mfma_kernel<<<dim3(32, 4, 4), dim3(192), 0, stream>>>(Q, Kb, attn_raw, N);
    topk_kernel<<<dim3(768), dim3(64), 0, stream>>>(attn_raw, invq, invk, temp, mix, Acomb);
    // ---- attn_out (T) -> XT1 ; x1 = x + po(attn_out) -> out ----
    attnv_kernel<<<dim3(N / 64, 4, 4), blk, 0, stream>>>(Acomb, V, XT1, N);
    wreg_gemm_kernel<192, float, true><<<dim3(3, N / 128, 4), blk, 0, stream>>>(Wpo, XT1, x, out, 192, 192, N, 128);
    // ---- FFN ----
    ln_t_kernel<<<ln_grid, blk, 0, stream>>>(out, ln2_w, ln2_b, XT0, N);
    for (int bp = 0; bp < 2; bp++) {
        const bf16* X2 = XT0 + (size_t)bp * 2 * N * 192;
        float* Ybp = out + (size_t)bp * 2 * 192 * N;
        wreg_gemm_kernel<192, bf16, false><<<dim3(8, N / 256, 2), blk, 0, stream>>>(Wfi, X2, nullptr, F1, 510, 192, N, 256);
        wreg_gemm_kernel<192, bf16, false><<<dim3(8, N / 256, 2), blk, 0, stream>>>(Wfi + (size_t)510 * 192, X2, nullptr, F2, 510, 192, N, 256);
        dwgelu_tile_kernel<<<dim3(16, 128, 2), blk, 0, stream>>>(F1, F2, ffn_dw, GT);
        wreg_gemm_kernel<512, float, true><<<dim3(3, N / 128, 2), blk, 0, stream>>>(Wfo, GT, Ybp, Ybp, 192, 512, N, 128);
    }
}

// Round 9
// 836.689 us; speedup vs baseline: 2.5185x; 1.0962x over previous
//
#include <hip/hip_runtime.h>
#include <hip/hip_bf16.h>

using bf16 = __hip_bfloat16;
typedef __attribute__((ext_vector_type(8))) short short8;
typedef __attribute__((ext_vector_type(4))) float f32x4;

// ---------------- helpers ----------------
__device__ __forceinline__ float tof(float v) { return v; }
__device__ __forceinline__ float tof(bf16 v) { return __bfloat162float(v); }
__device__ __forceinline__ float s2f(short s) {
    return __uint_as_float(((unsigned)(unsigned short)s) << 16);
}
__device__ __forceinline__ void storev(float* p, float v) { *p = v; }
__device__ __forceinline__ void storev(bf16* p, float v) { *p = __float2bfloat16(v); }
__device__ __forceinline__ short f2bf_bits(float v) {
    bf16 h = __float2bfloat16(v);
    return *(short*)&h;
}
__device__ __forceinline__ float wsum(float v) {
    #pragma unroll
    for (int o = 32; o > 0; o >>= 1) v += __shfl_xor(v, o);
    return v;
}
__device__ __forceinline__ float wmax(float v) {
    #pragma unroll
    for (int o = 32; o > 0; o >>= 1) v = fmaxf(v, __shfl_xor(v, o));
    return v;
}

// ---------------- weight preconvert: fp32 [Oreal][WLD] -> bf16 [Oalloc][KP], pad 0 ----
__global__ __launch_bounds__(256) void wconv_kernel(
    const float* __restrict__ src, bf16* __restrict__ dst,
    int Oreal, int Oalloc, int K, int KP, int WLD)
{
    const int idx = blockIdx.x * 256 + threadIdx.x;
    if (idx >= Oalloc * KP) return;
    const int o = idx / KP, k = idx % KP;
    float v = (o < Oreal && k < K) ? src[(size_t)o * WLD + k] : 0.f;
    dst[idx] = __float2bfloat16(v);
}

// ---------------- LayerNorm C=192: fp32 [b][192][N] -> bf16 [b][n][192] ----------------
__global__ __launch_bounds__(256) void ln_t_kernel(
    const float* __restrict__ X, const float* __restrict__ w,
    const float* __restrict__ bias, bf16* __restrict__ Y, int N)
{
    const int wv = threadIdx.x >> 6, ln_ = threadIdx.x & 63;
    const int p = blockIdx.x * 128 + wv * 32 + (ln_ & 31);   // flat pixel in B*N
    const int b = p >> 14, n = p & 16383;                    // N = 16384
    const int c0 = (ln_ >> 5) * 96;
    const float* xp = X + ((size_t)b * 192 + c0) * N + n;
    float s = 0.f, s2 = 0.f;
    #pragma unroll
    for (int c = 0; c < 96; c++) { float v = xp[(size_t)c * N]; s += v; s2 += v * v; }
    s += __shfl_xor(s, 32);
    s2 += __shfl_xor(s2, 32);
    const float mean = s * (1.f / 192.f);
    const float rstd = rsqrtf(s2 * (1.f / 192.f) - mean * mean + 1e-5f);
    bf16* yp = Y + ((size_t)(b * 16384 + n)) * 192 + c0;
    #pragma unroll
    for (int c = 0; c < 96; c += 2) {
        float v0 = (xp[(size_t)c * N] - mean) * rstd * w[c0 + c] + bias[c0 + c];
        float v1 = (xp[(size_t)(c + 1) * N] - mean) * rstd * w[c0 + c + 1] + bias[c0 + c + 1];
        unsigned u = (unsigned)(unsigned short)f2bf_bits(v0) |
                     ((unsigned)(unsigned short)f2bf_bits(v1) << 16);
        *(unsigned*)(yp + c) = u;
    }
}

// ---- weights-in-registers MFMA GEMM, XCD-swizzled: Y[b][o][n] = W[o][:].X[b][n][:] ----
template<int K, typename YT, bool RESID>
__global__ __launch_bounds__(256) void wreg_gemm_kernel(
    const bf16* __restrict__ Wb, const bf16* __restrict__ X,
    const float* __restrict__ Rsd, YT* __restrict__ Y,
    int O, int KS, int NROW, int NSTEP)
{
    constexpr int KST = K / 32;
    // bijective XCD swizzle: each XCD gets a contiguous work chunk, o fastest
    const int OT = gridDim.x, NT = gridDim.y;
    const int orig = blockIdx.x + OT * (blockIdx.y + NT * blockIdx.z);
    const int total = OT * NT * gridDim.z;
    const int qq = total >> 3, rr = total & 7;
    const int xcd = orig & 7, loc = orig >> 3;
    const int nw = (xcd < rr ? xcd * (qq + 1) : rr * (qq + 1) + (xcd - rr) * qq) + loc;
    const int o0 = (nw % OT) * 64;
    const int nbase = ((nw / OT) % NT) * NSTEP;
    const int b = nw / (OT * NT);

    const int wave = threadIdx.x >> 6, lane = threadIdx.x & 63;
    const int arow = lane & 15, kg = lane >> 4;

    short8 wf[KST];
    {
        const bf16* wp = Wb + (size_t)(o0 + wave * 16 + arow) * K + kg * 8;
        #pragma unroll
        for (int ks = 0; ks < KST; ks++) wf[ks] = *(const short8*)(wp + ks * 32);
    }
    const bf16* Xb = X + ((size_t)b * NROW + nbase) * KS;

    for (int nt = 0; nt < NSTEP; nt += 64) {
        f32x4 acc[4];
        #pragma unroll
        for (int s = 0; s < 4; s++) acc[s] = (f32x4){0.f, 0.f, 0.f, 0.f};
        #pragma unroll
        for (int s = 0; s < 4; s++) {
            const bf16* xp = Xb + (size_t)(nt + s * 16 + arow) * KS + kg * 8;
            #pragma unroll
            for (int ks = 0; ks < KST; ks++) {
                short8 bfr = *(const short8*)(xp + ks * 32);
                acc[s] = __builtin_amdgcn_mfma_f32_16x16x32_bf16(wf[ks], bfr, acc[s], 0, 0, 0);
            }
        }
        #pragma unroll
        for (int s = 0; s < 4; s++) {
            #pragma unroll
            for (int r = 0; r < 4; r++) {
                const int o = o0 + wave * 16 + kg * 4 + r;
                if (o < O) {
                    const size_t off = ((size_t)b * O + o) * NROW + nbase + nt + s * 16 + arow;
                    float v = acc[s][r];
                    if (RESID) v += Rsd[off];
                    storev(&Y[off], v);
                }
            }
        }
    }
}

// -------- tiled depthwise 3x3 (bf16 planes), vector LDS reads: 1 ch x 16 y x 128 x ----
__global__ __launch_bounds__(256) void dwconv3_tile_kernel(
    const bf16* __restrict__ X, const float* __restrict__ Wd, bf16* __restrict__ Y,
    int CH)
{
    __shared__ short sm[18][144];   // x0 at col 8; zero halos at 7 and 136
    const int b = blockIdx.z, ch = blockIdx.y;
    const int y0 = blockIdx.x * 16;
    const int tid = threadIdx.x;
    const size_t base = ((size_t)b * CH + ch) * 16384;

    for (int idx = tid; idx < 288; idx += 256) {
        const int r = idx >> 4, xc = idx & 15;
        const int yy = y0 - 1 + r;
        short8 v = {0, 0, 0, 0, 0, 0, 0, 0};
        if (yy >= 0 && yy < 128) v = *(const short8*)(X + base + yy * 128 + xc * 8);
        *(short8*)&sm[r][8 + xc * 8] = v;
    }
    if (tid < 18) { sm[tid][7] = 0; sm[tid][136] = 0; }
    __syncthreads();

    float wv[9];
    #pragma unroll
    for (int i = 0; i < 9; i++) wv[i] = Wd[ch * 9 + i];

    const int ty = tid >> 4, xg = tid & 15;
    float a[8] = {0.f, 0.f, 0.f, 0.f, 0.f, 0.f, 0.f, 0.f};
    #pragma unroll
    for (int dy = 0; dy < 3; dy++) {
        const short* row = &sm[ty + dy][xg * 8];
        short8 pv = *(const short8*)row;
        short8 cv = *(const short8*)(row + 8);
        short8 nv = *(const short8*)(row + 16);
        float u[10];
        u[0] = s2f(((short*)&pv)[7]);
        #pragma unroll
        for (int j = 0; j < 8; j++) u[j + 1] = s2f(((short*)&cv)[j]);
        u[9] = s2f(((short*)&nv)[0]);
        const float wa = wv[dy * 3], wb = wv[dy * 3 + 1], wc = wv[dy * 3 + 2];
        #pragma unroll
        for (int j = 0; j < 8; j++) a[j] += wa * u[j] + wb * u[j + 1] + wc * u[j + 2];
    }
    short8 ov;
    #pragma unroll
    for (int j = 0; j < 8; j++) ((short*)&ov)[j] = f2bf_bits(a[j]);
    *(short8*)(Y + base + (size_t)(y0 + ty) * 128 + xg * 8) = ov;
}

// ---- tiled fused dw3(f1)->gelu * dw3(f2) -> GT[b][n][512] ; 4 hc x 8 y x 128 x ------
// FB layout [b][1020][N]: f1 plane = hc, f2 plane = 510 + hc.
__global__ __launch_bounds__(256) void dwgelu_tile_kernel(
    const bf16* __restrict__ FB, const float* __restrict__ Wd, bf16* __restrict__ GT)
{
    __shared__ short s1[4][10][144];
    __shared__ short s2[4][10][144];
    __shared__ short ot[4][8][136];
    const int b = blockIdx.z;
    const int y0 = blockIdx.x * 8;
    const int hc0 = blockIdx.y * 4;
    const int tid = threadIdx.x;

    for (int idx = tid; idx < 640; idx += 256) {
        const int c = idx / 160, rem = idx % 160;
        const int r = rem >> 4, xc = rem & 15;
        const int yy = y0 - 1 + r;
        const int hc = hc0 + c;
        short8 v1 = {0,0,0,0,0,0,0,0}, v2 = v1;
        if (hc < 510 && yy >= 0 && yy < 128) {
            const size_t sp = (size_t)yy * 128 + xc * 8;
            v1 = *(const short8*)(FB + ((size_t)b * 1020 + hc) * 16384 + sp);
            v2 = *(const short8*)(FB + ((size_t)b * 1020 + 510 + hc) * 16384 + sp);
        }
        *(short8*)&s1[c][r][8 + xc * 8] = v1;
        *(short8*)&s2[c][r][8 + xc * 8] = v2;
    }
    if (tid < 40) {
        const int c = tid / 10, r = tid % 10;
        s1[c][r][7] = 0; s1[c][r][136] = 0;
        s2[c][r][7] = 0; s2[c][r][136] = 0;
    }
    __syncthreads();

    const int c = tid >> 6, y2 = (tid >> 4) & 3, xg = tid & 15;
    const int hc = hc0 + c;
    float w1[9], w2[9];
    #pragma unroll
    for (int i = 0; i < 9; i++) {
        w1[i] = (hc < 510) ? Wd[(size_t)hc * 9 + i] : 0.f;
        w2[i] = (hc < 510) ? Wd[(size_t)(510 + hc) * 9 + i] : 0.f;
    }
    #pragma unroll
    for (int t = 0; t < 2; t++) {
        const int yy = y2 * 2 + t;
        float d1[8] = {0.f,0.f,0.f,0.f,0.f,0.f,0.f,0.f};
        float d2[8] = {0.f,0.f,0.f,0.f,0.f,0.f,0.f,0.f};
        #pragma unroll
        for (int dy = 0; dy < 3; dy++) {
            const short* r1 = &s1[c][yy + dy][xg * 8];
            const short* r2 = &s2[c][yy + dy][xg * 8];
            short8 pa = *(const short8*)r1;
            short8 ca = *(const short8*)(r1 + 8);
            short8 na = *(const short8*)(r1 + 16);
            short8 pb = *(const short8*)r2;
            short8 cb = *(const short8*)(r2 + 8);
            short8 nb = *(const short8*)(r2 + 16);
            float u[10], v[10];
            u[0] = s2f(((short*)&pa)[7]);
            v[0] = s2f(((short*)&pb)[7]);
            #pragma unroll
            for (int j = 0; j < 8; j++) {
                u[j + 1] = s2f(((short*)&ca)[j]);
                v[j + 1] = s2f(((short*)&cb)[j]);
            }
            u[9] = s2f(((short*)&na)[0]);
            v[9] = s2f(((short*)&nb)[0]);
            const float a0 = w1[dy * 3], a1 = w1[dy * 3 + 1], a2 = w1[dy * 3 + 2];
            const float b0 = w2[dy * 3], b1 = w2[dy * 3 + 1], b2 = w2[dy * 3 + 2];
            #pragma unroll
            for (int j = 0; j < 8; j++) {
                d1[j] += a0 * u[j] + a1 * u[j + 1] + a2 * u[j + 2];
                d2[j] += b0 * v[j] + b1 * v[j + 1] + b2 * v[j + 2];
            }
        }
        short8 ov;
        #pragma unroll
        for (int j = 0; j < 8; j++) {
            float g = 0.5f * d1[j] * (1.f + erff(d1[j] * 0.70710678118654752f)) * d2[j];
            ((short*)&ov)[j] = f2bf_bits(g);
        }
        *(short8*)&ot[c][yy][xg * 8] = ov;
    }
    __syncthreads();
    for (int idx = tid; idx < 1024; idx += 256) {
        const int row = idx >> 7, col = idx & 127;
        short v0 = ot[0][row][col], v1 = ot[1][row][col];
        short v2 = ot[2][row][col], v3 = ot[3][row][col];
        uint2 pk;
        pk.x = (unsigned)(unsigned short)v0 | ((unsigned)(unsigned short)v1 << 16);
        pk.y = (unsigned)(unsigned short)v2 | ((unsigned)(unsigned short)v3 << 16);
        *(uint2*)(GT + ((size_t)b * 16384 + y0 * 128 + idx) * 512 + hc0) = pk;
    }
}

// ---------------- row L2 norms (bf16 rows of length N), short8 loads ----------------
__global__ __launch_bounds__(256) void rownorm_kernel(
    const bf16* __restrict__ X, float* __restrict__ inv, int N)
{
    const int row = blockIdx.x;
    const bf16* p = X + (size_t)row * N;
    float s = 0.f;
    for (int i = threadIdx.x * 8; i < N; i += 2048) {
        short8 v = *(const short8*)(p + i);
        #pragma unroll
        for (int j = 0; j < 8; j++) { float f = s2f(((short*)&v)[j]); s += f * f; }
    }
    s = wsum(s);
    __shared__ float red[4];
    if ((threadIdx.x & 63) == 0) red[threadIdx.x >> 6] = s;
    __syncthreads();
    if (threadIdx.x == 0) {
        float t = red[0] + red[1] + red[2] + red[3];
        inv[row] = 1.f / fmaxf(sqrtf(t), 1e-12f);
    }
}

// ------- gram via MFMA: attn_raw[bh][c][d] += sum_n q[c,n]*k[d,n] over n-chunk --------
__global__ __launch_bounds__(192) void gram_mfma_kernel(
    const bf16* __restrict__ Q, const bf16* __restrict__ K,
    float* __restrict__ attn_raw, int N)
{
    const int b = blockIdx.z, h = blockIdx.y;
    const int n0base = blockIdx.x * 512;
    const int wave = threadIdx.x >> 6, lane = threadIdx.x & 63;
    const int arow = lane & 15, kg = lane >> 4;
    const bf16* Qb = Q + ((size_t)b * 192 + h * 48 + wave * 16 + arow) * N;
    const bf16* Kb = K + ((size_t)b * 192 + h * 48) * N;

    f32x4 acc[3];
    #pragma unroll
    for (int di = 0; di < 3; di++) acc[di] = (f32x4){0.f, 0.f, 0.f, 0.f};

    #pragma unroll 4
    for (int t = 0; t < 16; t++) {
        const int n0 = n0base + t * 32 + kg * 8;
        short8 a = *(const short8*)(Qb + n0);
        #pragma unroll
        for (int di = 0; di < 3; di++) {
            short8 bfr = *(const short8*)(Kb + (size_t)(di * 16 + arow) * N + n0);
            acc[di] = __builtin_amdgcn_mfma_f32_16x16x32_bf16(a, bfr, acc[di], 0, 0, 0);
        }
    }
    float* A = attn_raw + (size_t)(b * 4 + h) * 2304;
    const int c = wave * 16 + kg * 4;
    #pragma unroll
    for (int di = 0; di < 3; di++)
        #pragma unroll
        for (int r = 0; r < 4; r++)
            atomicAdd(&A[(c + r) * 48 + di * 16 + arow], acc[di][r]);
}

// ---------------- top-k(4 ways) sparsified softmax combine ----------------
__global__ __launch_bounds__(64) void topk_kernel(
    const float* __restrict__ attn_raw, const float* __restrict__ invq,
    const float* __restrict__ invk, const float* __restrict__ temp,
    const float* __restrict__ mix, float* __restrict__ Acomb)
{
    const int rowid = blockIdx.x;  // bh*48 + c
    const int c = rowid % 48, bh = rowid / 48, h = bh & 3, b = bh >> 2;
    const int lane = threadIdx.x;
    __shared__ float a[48];
    const float iq = invq[b * 192 + h * 48 + c] * temp[h];
    if (lane < 48)
        a[lane] = attn_raw[(size_t)bh * 2304 + c * 48 + lane] * iq * invk[b * 192 + h * 48 + lane];
    __syncthreads();
    const float av = (lane < 48) ? a[lane] : -INFINITY;
    int cnt_gt = 0, cnt_ge = 0;
    if (lane < 48) {
        for (int j = 0; j < 48; j++) { cnt_gt += (a[j] > av); cnt_ge += (a[j] >= av); }
    }
    const float m = wmax(av);
    const float p = (lane < 48) ? expf(av - m) : 0.f;
    float coeff = 0.f;
    const int kks[4] = {24, 32, 36, 38};
    #pragma unroll
    for (int i = 0; i < 4; i++) {
        const int kk = kks[i];
        float cand = (lane < 48 && cnt_gt < kk && cnt_ge >= kk) ? av : -INFINITY;
        cand = wmax(cand);
        const bool pass = (lane < 48) && (av >= cand);
        float z = wsum(pass ? p : 0.f);
        coeff += pass ? (mix[i] / z) : 0.f;
    }
    if (lane < 48) Acomb[(size_t)bh * 2304 + c * 48 + lane] = p * coeff;
}

// ---------------- attn_out (T-layout bf16 [b][n][192]) = Acomb @ v ----------------
__global__ __launch_bounds__(256) void attnv_kernel(
    const float* __restrict__ Acomb, const bf16* __restrict__ V,
    bf16* __restrict__ OT, int N)
{
    __shared__ float As[48][48];
    __shared__ float vs[48][64];
    __shared__ bf16 ot[64][48];
    const int b = blockIdx.z, h = blockIdx.y;
    const int n0 = blockIdx.x * 64;
    const float* Ap = Acomb + (size_t)(b * 4 + h) * 2304;
    for (int i = threadIdx.x; i < 2304; i += 256) As[i / 48][i % 48] = Ap[i];
    const bf16* Vb = V + ((size_t)b * 192 + h * 48) * N;
    for (int i = threadIdx.x; i < 3072; i += 256) {
        const int r = i >> 6, cn = i & 63;
        vs[r][cn] = tof(Vb[(size_t)r * N + n0 + cn]);
    }
    __syncthreads();
    const int nl = threadIdx.x & 63;
    const int cg = threadIdx.x >> 6;
    for (int c = cg * 12; c < cg * 12 + 12; c++) {
        float s = 0.f;
        #pragma unroll
        for (int d = 0; d < 48; d++) s += As[c][d] * vs[d][nl];
        ot[nl][c] = __float2bfloat16(s);
    }
    __syncthreads();
    for (int idx = threadIdx.x; idx < 384; idx += 256) {
        const int r = idx / 6, q = idx % 6;
        *(uint4*)((char*)&OT[((size_t)b * N + n0 + r) * 192 + h * 48] + q * 16) =
            *(uint4*)((char*)&ot[r][0] + q * 16);
    }
}

// ---------------- launch ----------------
extern "C" void kernel_launch(void* const* d_in, const int* in_sizes, int n_in,
                              void* d_out, int out_size, void* d_ws, size_t ws_size,
                              hipStream_t stream)
{
    const float* x       = (const float*)d_in[0];
    const float* y       = (const float*)d_in[1];
    const float* ln1_w   = (const float*)d_in[2];
    const float* ln1_b   = (const float*)d_in[3];
    const float* ln2_w   = (const float*)d_in[4];
    const float* ln2_b   = (const float*)d_in[5];
    const float* kv_w    = (const float*)d_in[6];
    const float* kv_dw   = (const float*)d_in[7];
    const float* q_w     = (const float*)d_in[8];
    const float* q_dw    = (const float*)d_in[9];
    const float* po_w    = (const float*)d_in[10];
    const float* temp    = (const float*)d_in[11];
    const float* mix     = (const float*)d_in[12];
    const float* ffn_in_w  = (const float*)d_in[13];
    const float* ffn_dw    = (const float*)d_in[14];
    const float* ffn_out_w = (const float*)d_in[15];
    float* out = (float*)d_out;

    const int N = 16384;
    const size_t TB = (size_t)4 * N * 192 * 2;   // 25,165,824 bytes

    char* ws = (char*)d_ws;
    bf16* XT0 = (bf16*)ws;                        // yn / xn / xn2 (T-layout)
    bf16* XT1 = (bf16*)(ws + TB);                 // q/k/v_pre then attn_outT
    bf16* Q   = (bf16*)(ws + 2 * TB);
    bf16* Kb  = (bf16*)(ws + 3 * TB);
    bf16* V   = (bf16*)(ws + 4 * TB);
    float* S  = (float*)(ws + 5 * TB);            // @ 125,829,120
    float* invq = S;
    float* invk = S + 768;
    float* attn_raw = S + 1536;
    float* Acomb = attn_raw + 16 * 48 * 48;       // S region < 310 KB
    // bf16 weights after S region
    bf16* Wq  = (bf16*)(ws + 5 * TB + 331776);
    bf16* Wkv = Wq + 36864;        // 384x192
    bf16* Wpo = Wkv + 73728;       // 192x192
    bf16* Wfi = Wpo + 36864;       // 1024x192 (1020 real + 4 zero rows)
    bf16* Wfo = Wfi + 196608;      // 192x512  (K padded 510->512)
    // FFN overlay (attention buffers dead): FB [2][1020][N] then GT [2][N][512]
    bf16* FB = (bf16*)(ws + TB);
    bf16* GT = (bf16*)(ws + TB + (size_t)66846720);   // ends at 125,566,976 < 5*TB

    const dim3 blk(256);
    const dim3 ln_grid(4 * N / 128);
    const dim3 dwg(8, 192, 4);

    // ---- preconvert weights to bf16 ----
    wconv_kernel<<<dim3((192 * 192 + 255) / 256), blk, 0, stream>>>(q_w, Wq, 192, 192, 192, 192, 192);
    wconv_kernel<<<dim3((384 * 192 + 255) / 256), blk, 0, stream>>>(kv_w, Wkv, 384, 384, 192, 192, 192);
    wconv_kernel<<<dim3((192 * 192 + 255) / 256), blk, 0, stream>>>(po_w, Wpo, 192, 192, 192, 192, 192);
    wconv_kernel<<<dim3((1024 * 192 + 255) / 256), blk, 0, stream>>>(ffn_in_w, Wfi, 1020, 1024, 192, 192, 192);
    wconv_kernel<<<dim3((192 * 512 + 255) / 256), blk, 0, stream>>>(ffn_out_w, Wfo, 192, 192, 510, 512, 510);

    // ---- q path ----
    ln_t_kernel<<<ln_grid, blk, 0, stream>>>(y, ln1_w, ln1_b, XT0, N);
    wreg_gemm_kernel<192, bf16, false><<<dim3(3, N / 128, 4), blk, 0, stream>>>(Wq, XT0, nullptr, XT1, 192, 192, N, 128);
    dwconv3_tile_kernel<<<dwg, blk, 0, stream>>>(XT1, q_dw, Q, 192);
    // ---- k, v path ----
    ln_t_kernel<<<ln_grid, blk, 0, stream>>>(x, ln1_w, ln1_b, XT0, N);
    wreg_gemm_kernel<192, bf16, false><<<dim3(3, N / 128, 4), blk, 0, stream>>>(Wkv, XT0, nullptr, XT1, 192, 192, N, 128);
    dwconv3_tile_kernel<<<dwg, blk, 0, stream>>>(XT1, kv_dw, Kb, 192);
    wreg_gemm_kernel<192, bf16, false><<<dim3(3, N / 128, 4), blk, 0, stream>>>(Wkv + 192 * 192, XT0, nullptr, XT1, 192, 192, N, 128);
    dwconv3_tile_kernel<<<dwg, blk, 0, stream>>>(XT1, kv_dw + 192 * 9, V, 192);
    // ---- norms, attention matrix, combine ----
    rownorm_kernel<<<dim3(768), blk, 0, stream>>>(Q, invq, N);
    rownorm_kernel<<<dim3(768), blk, 0, stream>>>(Kb, invk, N);
    hipMemsetAsync(attn_raw, 0, 16 * 48 * 48 * 4, stream);
    gram_mfma_kernel<<<dim3(32, 4, 4), dim3(192), 0, stream>>>(Q, Kb, attn_raw, N);
    topk_kernel<<<dim3(768), dim3(64), 0, stream>>>(attn_raw, invq, invk, temp, mix, Acomb);
    // ---- attn_out (T) -> XT1 ; x1 = x + po(attn_out) -> out ----
    attnv_kernel<<<dim3(N / 64, 4, 4), blk, 0, stream>>>(Acomb, V, XT1, N);
    wreg_gemm_kernel<192, float, true><<<dim3(3, N / 128, 4), blk, 0, stream>>>(Wpo, XT1, x, out, 192, 192, N, 128);
    // ---- FFN ----
    ln_t_kernel<<<ln_grid, blk, 0, stream>>>(out, ln2_w, ln2_b, XT0, N);
    for (int bp = 0; bp < 2; bp++) {
        const bf16* X2 = XT0 + (size_t)bp * 2 * N * 192;
        float* Ybp = out + (size_t)bp * 2 * 192 * N;
        wreg_gemm_kernel<192, bf16, false><<<dim3(16, N / 256, 2), blk, 0, stream>>>(Wfi, X2, nullptr, FB, 1020, 192, N, 256);
        dwgelu_tile_kernel<<<dim3(16, 128, 2), blk, 0, stream>>>(FB, ffn_dw, GT);
        wreg_gemm_kernel<512, float, true><<<dim3(3, N / 128, 2), blk, 0, stream>>>(Wfo, GT, Ybp, Ybp, 192, 512, N, 128);
    }
}